// Round 2
// baseline (444.996 us; speedup 1.0000x reference)
//
#include <hip/hip_runtime.h>
#include <cstdint>
#include <cstddef>

typedef unsigned short u16;
typedef unsigned int u32;

#define NT 100000
#define NC 25000
#define ETT 800000
#define ECT 400000
#define SLOPE 0.2f
#define LOG2E 1.4426950408889634f
#define OFFS (NT + 4)           // padded stride for offset arrays (16B-aligned)

// bucket-binned CSR build
#define NBK 782                 // ceil(NT/128) buckets of 128 nodes
#define NBLK 256                // binning blocks
#define CHT ((ETT + NBLK - 1) / NBLK)   // 3125 tt edges / block
#define CHC ((ECT + NBLK - 1) / NBLK)   // 1563 ct edges / block
#define TOTC (3 * NBK * NBLK)           // 600576 counts
#define NSB ((TOTC + 2047) / 2048)      // 294 scan blocks

typedef __attribute__((ext_vector_type(8))) short bf16x8;
typedef __attribute__((ext_vector_type(4))) float f32x4;

__device__ __forceinline__ u16 f2bf(float f) {
  u32 u = __float_as_uint(f);
  u32 r = (u >> 16) & 1u;
  return (u16)((u + 0x7fffu + r) >> 16);
}
__device__ __forceinline__ float lof(u32 p) { return __uint_as_float(p << 16); }
__device__ __forceinline__ float hif(u32 p) { return __uint_as_float(p & 0xffff0000u); }

// ---------- K1: h_t(bf16) = relu(x_t @ Wpt + b); aD_ct = relu(h_t) @ fold_cd ----------
__global__ __launch_bounds__(256) void pre_t_kernel(const float* __restrict__ in,
    const float* __restrict__ W, const float* __restrict__ bias,
    const float* __restrict__ fold_cd, u16* __restrict__ h_t,
    float* __restrict__ aD, int N)
{
  __shared__ float s_in[32][33];
  __shared__ float s_W[32][128];
  __shared__ float s_fold[512];
  const int t = threadIdx.x;
  s_fold[t] = fold_cd[t];
  s_fold[t + 256] = fold_cd[t + 256];
  const int row0 = blockIdx.x * 32;
  const int rl = t >> 3, cg = t & 7;
  const int gr = row0 + rl;
  float acc[4][4];
  for (int g = 0; g < 4; ++g)
    for (int j = 0; j < 4; ++j)
      acc[g][j] = bias[g * 32 + cg * 4 + j];
  for (int kc = 0; kc < 64; kc += 32) {
    {
      float4 f = make_float4(0.f, 0.f, 0.f, 0.f);
      if (gr < N) f = *(const float4*)(in + (size_t)gr * 64 + kc + cg * 4);
      s_in[rl][cg * 4 + 0] = f.x; s_in[rl][cg * 4 + 1] = f.y;
      s_in[rl][cg * 4 + 2] = f.z; s_in[rl][cg * 4 + 3] = f.w;
    }
    for (int j = 0; j < 4; ++j) {
      const int idx = t + j * 256;
      const int k = idx >> 5, c4 = (idx & 31) * 4;
      *(float4*)&s_W[k][c4] = *(const float4*)(W + (size_t)(kc + k) * 128 + c4);
    }
    __syncthreads();
#pragma unroll 8
    for (int k = 0; k < 32; ++k) {
      const float a = s_in[rl][k];
      for (int g = 0; g < 4; ++g) {
        const float4 w = *(const float4*)&s_W[k][g * 32 + cg * 4];
        acc[g][0] = fmaf(a, w.x, acc[g][0]);
        acc[g][1] = fmaf(a, w.y, acc[g][1]);
        acc[g][2] = fmaf(a, w.z, acc[g][2]);
        acc[g][3] = fmaf(a, w.w, acc[g][3]);
      }
    }
    __syncthreads();
  }
  if (gr < N) {
    float p0 = 0.f, p1 = 0.f, p2 = 0.f, p3 = 0.f;
    for (int g = 0; g < 4; ++g) {
      for (int j = 0; j < 4; ++j) acc[g][j] = fmaxf(acc[g][j], 0.f);
      uint2 pk;
      pk.x = (u32)f2bf(acc[g][0]) | ((u32)f2bf(acc[g][1]) << 16);
      pk.y = (u32)f2bf(acc[g][2]) | ((u32)f2bf(acc[g][3]) << 16);
      *(uint2*)(h_t + (size_t)gr * 128 + g * 32 + cg * 4) = pk;
      for (int j = 0; j < 4; ++j) {
        const int col = g * 32 + cg * 4 + j;
        const float4 f4 = *(const float4*)&s_fold[col * 4];
        const float a = acc[g][j];
        p0 = fmaf(a, f4.x, p0); p1 = fmaf(a, f4.y, p1);
        p2 = fmaf(a, f4.z, p2); p3 = fmaf(a, f4.w, p3);
      }
    }
    for (int m = 1; m < 8; m <<= 1) {
      p0 += __shfl_xor(p0, m); p1 += __shfl_xor(p1, m);
      p2 += __shfl_xor(p2, m); p3 += __shfl_xor(p3, m);
    }
    if (cg == 0) *(float4*)(aD + (size_t)gr * 4) = make_float4(p0, p1, p2, p3);
  }
}

// ---------- weight prep: frag-linear bf16 B for MFMA (+ fold cols) + fold_cd + cbias ----------
// NOTE: attention-fold columns (fS/fD/fold_cd) are pre-scaled by log2(e) so the
// gather kernel can use native exp2 (LeakyReLU is positively homogeneous).
__global__ __launch_bounds__(256) void prep_kernel(
    const float* __restrict__ Wsd, const float* __restrict__ AsSd, const float* __restrict__ AdSd,
    const float* __restrict__ Wds, const float* __restrict__ AsDs, const float* __restrict__ AdDs,
    const float* __restrict__ Wout, u16* __restrict__ bf_sd, u16* __restrict__ bf_ds,
    u16* __restrict__ bf_out,
    const float* __restrict__ Wcd, const float* __restrict__ attD,
    const float* __restrict__ bsd, const float* __restrict__ bds, const float* __restrict__ bct,
    float* __restrict__ fold_cd, float* __restrict__ cbias)
{
  const int b = blockIdx.x;
  const int tid = threadIdx.x;
  if (b == 3) {
    if (tid < 128) {
      for (int h = 0; h < 4; ++h) {
        float s = 0.f;
        for (int c = 0; c < 32; ++c)
          s = fmaf(Wcd[tid * 128 + h * 32 + c], attD[h * 32 + c], s);
        fold_cd[tid * 4 + h] = s * LOG2E;
      }
      cbias[tid] = 0.25f * bsd[tid] + 0.25f * bds[tid] + 0.5f * bct[tid];
    }
    return;
  }
  __shared__ float fS[512], fD[512];
  const float* W = (b == 0) ? Wsd : (b == 1) ? Wds : Wout;
  const float* As = (b == 0) ? AsSd : AsDs;
  const float* Ad = (b == 0) ? AdSd : AdDs;
  u16* out = (b == 0) ? bf_sd : (b == 1) ? bf_ds : bf_out;
  const int tiles = (b == 2) ? 8 : 9;
  if (b < 2) {
    if (tid < 128) {
      for (int h = 0; h < 4; ++h) {
        float s1 = 0.f, s2 = 0.f;
        for (int c = 0; c < 32; ++c) {
          const float wv = W[tid * 128 + h * 32 + c];
          s1 = fmaf(wv, As[h * 32 + c], s1);
          s2 = fmaf(wv, Ad[h * 32 + c], s2);
        }
        fS[tid * 4 + h] = s1 * LOG2E; fD[tid * 4 + h] = s2 * LOG2E;
      }
    }
    __syncthreads();
  }
  const int total = tiles * 4 * 64 * 8;
  for (int i = tid; i < total; i += 256) {
    const int j = i & 7, lane = (i >> 3) & 63, ks = (i >> 9) & 3, t = i >> 11;
    const int k = ks * 32 + (lane >> 4) * 8 + j;
    const int n = t * 16 + (lane & 15);
    float v;
    if (n < 128) v = W[k * 128 + n];
    else if (n < 132) v = fS[k * 4 + (n - 128)];
    else if (n < 136) v = fD[k * 4 + (n - 132)];
    else v = 0.f;
    out[i] = f2bf(v);
  }
}

// ---------- fused MFMA GEMM x2 (sd + ds), N=144 each: bf16 out + aS/aD logits ----------
__global__ __launch_bounds__(256) void mfma_logits2_kernel(
    const short* __restrict__ A, const short* __restrict__ Bsd, const short* __restrict__ Bds,
    u16* __restrict__ hs, float* __restrict__ aSsd, float* __restrict__ aDsd,
    u16* __restrict__ hd, float* __restrict__ aSds, float* __restrict__ aDds, int M)
{
  __shared__ __align__(16) float lds[4][16][148];
  const int wv = threadIdx.x >> 6, lane = threadIdx.x & 63;
  const int quad = lane >> 4, l16 = lane & 15;
  const int row0 = blockIdx.x * 64 + wv * 16;
  const int arow = min(row0 + l16, M - 1);
  const short* ap = A + (size_t)arow * 128 + quad * 8;
  bf16x8 af[4];
  for (int ks = 0; ks < 4; ++ks) af[ks] = *(const bf16x8*)(ap + ks * 32);
  const int row = row0 + l16;
  const int idx = lane & 7, rr = lane >> 3;
  for (int pass = 0; pass < 2; ++pass) {
    const short* B = pass ? Bds : Bsd;
    u16* outb = pass ? hd : hs;
    float* aS = pass ? aSds : aSsd;
    float* aD = pass ? aDds : aDsd;
    f32x4 acc[9];
    for (int t = 0; t < 9; ++t) acc[t] = (f32x4){0.f, 0.f, 0.f, 0.f};
    for (int ks = 0; ks < 4; ++ks)
      for (int t = 0; t < 9; ++t) {
        const bf16x8 bf = *(const bf16x8*)(B + ((t * 4 + ks) * 64 + lane) * 8);
        acc[t] = __builtin_amdgcn_mfma_f32_16x16x32_bf16(af[ks], bf, acc[t], 0, 0, 0);
      }
    for (int t = 0; t < 9; ++t)
      for (int r = 0; r < 4; ++r)
        lds[wv][quad * 4 + r][t * 16 + l16] = acc[t][r];
    __syncthreads();
    if (row < M) {
      for (int g = 0; g < 8; ++g) {
        const f32x4 v = *(const f32x4*)&lds[wv][l16][g * 16 + quad * 4];
        uint2 pk;
        pk.x = (u32)f2bf(v[0]) | ((u32)f2bf(v[1]) << 16);
        pk.y = (u32)f2bf(v[2]) | ((u32)f2bf(v[3]) << 16);
        *(uint2*)(outb + (size_t)row * 128 + g * 16 + quad * 4) = pk;
      }
    }
    for (int p = 0; p < 2; ++p) {
      const int lr = p * 8 + rr;
      const int n = row0 + lr;
      if (n < M) {
        const float v = lds[wv][lr][128 + idx];
        if (idx < 4) aS[(size_t)n * 4 + idx] = v;
        else aD[(size_t)n * 4 + idx - 4] = v;
      }
    }
    __syncthreads();
  }
}

// ---------- MFMA GEMM, N=128 (8 tiles) + bias -> fp32 out ----------
__global__ __launch_bounds__(256) void mfma_out_kernel(
    const short* __restrict__ A, const short* __restrict__ B,
    const float* __restrict__ bias, float* __restrict__ out, int M)
{
  __shared__ __align__(16) float lds[4][16][132];
  const int wv = threadIdx.x >> 6, lane = threadIdx.x & 63;
  const int quad = lane >> 4, l16 = lane & 15;
  const int row0 = blockIdx.x * 64 + wv * 16;
  const int arow = min(row0 + l16, M - 1);
  const short* ap = A + (size_t)arow * 128 + quad * 8;
  bf16x8 af[4];
  for (int ks = 0; ks < 4; ++ks) af[ks] = *(const bf16x8*)(ap + ks * 32);
  f32x4 acc[8];
  for (int t = 0; t < 8; ++t) acc[t] = (f32x4){0.f, 0.f, 0.f, 0.f};
  for (int ks = 0; ks < 4; ++ks)
    for (int t = 0; t < 8; ++t) {
      const bf16x8 bf = *(const bf16x8*)(B + ((t * 4 + ks) * 64 + lane) * 8);
      acc[t] = __builtin_amdgcn_mfma_f32_16x16x32_bf16(af[ks], bf, acc[t], 0, 0, 0);
    }
  for (int t = 0; t < 8; ++t)
    for (int r = 0; r < 4; ++r)
      lds[wv][quad * 4 + r][t * 16 + l16] = acc[t][r];
  __syncthreads();
  const int row = row0 + l16;
  if (row < M) {
    for (int g = 0; g < 8; ++g) {
      const int col = g * 16 + quad * 4;
      f32x4 v = *(const f32x4*)&lds[wv][l16][col];
      const f32x4 b4 = *(const f32x4*)(bias + col);
      v = v + b4;
      *(f32x4*)(out + (size_t)row * 128 + col) = v;
    }
  }
}

// ---------- K4: hcs = relu(x_c @ Wpc + b) @ Wcs (bf16) + a_s_ct ----------
__global__ __launch_bounds__(256) void ctx_kernel(const float* __restrict__ x_c,
    const float* __restrict__ Wpc, const float* __restrict__ bpc,
    const float* __restrict__ Wcs, const float* __restrict__ attS,
    u16* __restrict__ hc_bf, float* __restrict__ aS, int N)
{
  __shared__ float s_in[32][33];
  __shared__ float s_W[32][128];
  __shared__ float s_h[32][132];
  const int t = threadIdx.x;
  const int row0 = blockIdx.x * 32;
  const int rl = t >> 3, cg = t & 7;
  const int gr = row0 + rl;
  {
    float4 f = make_float4(0.f, 0.f, 0.f, 0.f);
    if (gr < N) f = *(const float4*)(x_c + (size_t)gr * 32 + cg * 4);
    s_in[rl][cg * 4 + 0] = f.x; s_in[rl][cg * 4 + 1] = f.y;
    s_in[rl][cg * 4 + 2] = f.z; s_in[rl][cg * 4 + 3] = f.w;
  }
  for (int j = 0; j < 4; ++j) {
    const int idx = t + j * 256;
    const int k = idx >> 5, c4 = (idx & 31) * 4;
    *(float4*)&s_W[k][c4] = *(const float4*)(Wpc + (size_t)k * 128 + c4);
  }
  __syncthreads();
  float acc[4][4];
  for (int g = 0; g < 4; ++g)
    for (int j = 0; j < 4; ++j) acc[g][j] = bpc[g * 32 + cg * 4 + j];
#pragma unroll 8
  for (int k = 0; k < 32; ++k) {
    const float a = s_in[rl][k];
    for (int g = 0; g < 4; ++g) {
      const float4 w = *(const float4*)&s_W[k][g * 32 + cg * 4];
      acc[g][0] = fmaf(a, w.x, acc[g][0]);
      acc[g][1] = fmaf(a, w.y, acc[g][1]);
      acc[g][2] = fmaf(a, w.z, acc[g][2]);
      acc[g][3] = fmaf(a, w.w, acc[g][3]);
    }
  }
  for (int g = 0; g < 4; ++g)
    *(float4*)&s_h[rl][g * 32 + cg * 4] =
        make_float4(fmaxf(acc[g][0], 0.f), fmaxf(acc[g][1], 0.f),
                    fmaxf(acc[g][2], 0.f), fmaxf(acc[g][3], 0.f));
  __syncthreads();
  float acc2[4][4];
  for (int g = 0; g < 4; ++g)
    for (int j = 0; j < 4; ++j) acc2[g][j] = 0.f;
  for (int kc = 0; kc < 128; kc += 32) {
    for (int j = 0; j < 4; ++j) {
      const int idx = t + j * 256;
      const int k = idx >> 5, c4 = (idx & 31) * 4;
      *(float4*)&s_W[k][c4] = *(const float4*)(Wcs + (size_t)(kc + k) * 128 + c4);
    }
    __syncthreads();
#pragma unroll 8
    for (int k = 0; k < 32; ++k) {
      const float a = s_h[rl][kc + k];
      for (int g = 0; g < 4; ++g) {
        const float4 w = *(const float4*)&s_W[k][g * 32 + cg * 4];
        acc2[g][0] = fmaf(a, w.x, acc2[g][0]);
        acc2[g][1] = fmaf(a, w.y, acc2[g][1]);
        acc2[g][2] = fmaf(a, w.z, acc2[g][2]);
        acc2[g][3] = fmaf(a, w.w, acc2[g][3]);
      }
    }
    __syncthreads();
  }
  if (gr < N) {
    float pS[4];
    for (int g = 0; g < 4; ++g) {
      uint2 pk;
      pk.x = (u32)f2bf(acc2[g][0]) | ((u32)f2bf(acc2[g][1]) << 16);
      pk.y = (u32)f2bf(acc2[g][2]) | ((u32)f2bf(acc2[g][3]) << 16);
      *(uint2*)(hc_bf + (size_t)gr * 128 + g * 32 + cg * 4) = pk;
      const float4 as4 = *(const float4*)(attS + g * 32 + cg * 4);
      pS[g] = acc2[g][0] * as4.x + acc2[g][1] * as4.y + acc2[g][2] * as4.z + acc2[g][3] * as4.w;
    }
    for (int m = 1; m < 8; m <<= 1)
      for (int g = 0; g < 4; ++g) pS[g] += __shfl_xor(pS[g], m);
    if (cg == 0)
      *(float4*)(aS + (size_t)gr * 4) =
          make_float4(pS[0] * LOG2E, pS[1] * LOG2E, pS[2] * LOG2E, pS[3] * LOG2E);
  }
}

// ---------- bucket-binned CSR build (no global atomics) ----------
__global__ __launch_bounds__(256) void hist_blk_kernel(const int* __restrict__ tt_src,
    const int* __restrict__ tt_dst, const int* __restrict__ ect_d, int* __restrict__ cntblk)
{
  __shared__ int h[3 * NBK];
  const int t = threadIdx.x, b = blockIdx.x;
  for (int i = t; i < 3 * NBK; i += 256) h[i] = 0;
  __syncthreads();
  const int lo = b * CHT, hi = min(lo + CHT, ETT);
  for (int i = lo + t; i < hi; i += 256) {
    atomicAdd(&h[tt_dst[i] >> 7], 1);
    atomicAdd(&h[NBK + (tt_src[i] >> 7)], 1);
  }
  const int lo2 = b * CHC, hi2 = min(lo2 + CHC, ECT);
  for (int i = lo2 + t; i < hi2; i += 256)
    atomicAdd(&h[2 * NBK + (ect_d[i] >> 7)], 1);
  __syncthreads();
  for (int i = t; i < 3 * NBK; i += 256)
    cntblk[(size_t)i * NBLK + b] = h[i];
}

__global__ __launch_bounds__(256) void scan2_blk_kernel(const int* __restrict__ in,
    int* __restrict__ out, int* __restrict__ bsum)
{
  const int t = threadIdx.x, b = blockIdx.x;
  const int idx = b * 2048 + t * 8;
  int v[8];
  int s = 0;
  if (idx < TOTC) {
    const int4 q0 = *(const int4*)(in + idx);
    const int4 q1 = *(const int4*)(in + idx + 4);
    int x;
    x = q0.x; v[0] = s; s += x;  x = q0.y; v[1] = s; s += x;
    x = q0.z; v[2] = s; s += x;  x = q0.w; v[3] = s; s += x;
    x = q1.x; v[4] = s; s += x;  x = q1.y; v[5] = s; s += x;
    x = q1.z; v[6] = s; s += x;  x = q1.w; v[7] = s; s += x;
  } else {
    for (int j = 0; j < 8; ++j) v[j] = 0;
  }
  __shared__ int sh[256];
  sh[t] = s;
  __syncthreads();
  for (int d = 1; d < 256; d <<= 1) {
    const int u = (t >= d) ? sh[t - d] : 0;
    __syncthreads();
    sh[t] += u;
    __syncthreads();
  }
  const int excl = (t == 0) ? 0 : sh[t - 1];
  if (idx < TOTC) {
    int4 q0, q1;
    q0.x = excl + v[0]; q0.y = excl + v[1]; q0.z = excl + v[2]; q0.w = excl + v[3];
    q1.x = excl + v[4]; q1.y = excl + v[5]; q1.z = excl + v[6]; q1.w = excl + v[7];
    *(int4*)(out + idx) = q0;
    *(int4*)(out + idx + 4) = q1;
  }
  if (t == 255) bsum[b] = sh[255];
}

__global__ __launch_bounds__(512) void scan2_top_kernel(const int* __restrict__ bsum,
    int* __restrict__ bpre)
{
  __shared__ int sh[512];
  const int t = threadIdx.x;
  const int orig = (t < NSB) ? bsum[t] : 0;
  sh[t] = orig;
  __syncthreads();
  for (int d = 1; d < 512; d <<= 1) {
    const int v = (t >= d) ? sh[t - d] : 0;
    __syncthreads();
    sh[t] += v;
    __syncthreads();
  }
  if (t < NSB) bpre[t] = sh[t] - orig;
}

__global__ __launch_bounds__(256) void scan2_add_kernel(const int* __restrict__ bpre,
    int* __restrict__ out)
{
  const int t = threadIdx.x, b = blockIdx.x;
  const int bp = bpre[b];
  const int idx = b * 2048 + t * 8;
  if (idx < TOTC) {
    int4 q0 = *(const int4*)(out + idx);
    int4 q1 = *(const int4*)(out + idx + 4);
    q0.x += bp; q0.y += bp; q0.z += bp; q0.w += bp;
    q1.x += bp; q1.y += bp; q1.z += bp; q1.w += bp;
    *(int4*)(out + idx) = q0;
    *(int4*)(out + idx + 4) = q1;
  }
}

__global__ __launch_bounds__(256) void bin_kernel(const int* __restrict__ tt_src,
    const int* __restrict__ tt_dst, const int* __restrict__ ect_s, const int* __restrict__ ect_d,
    const int* __restrict__ scanned, u32* __restrict__ bin)
{
  __shared__ int cur[3 * NBK];
  const int t = threadIdx.x, b = blockIdx.x;
  for (int i = t; i < 3 * NBK; i += 256)
    cur[i] = scanned[(size_t)i * NBLK + b];
  __syncthreads();
  const int lo = b * CHT, hi = min(lo + CHT, ETT);
  for (int i = lo + t; i < hi; i += 256) {
    const int s = tt_src[i], d = tt_dst[i];
    int p = atomicAdd(&cur[d >> 7], 1);
    bin[p] = ((u32)(d & 127) << 17) | (u32)s;
    p = atomicAdd(&cur[NBK + (s >> 7)], 1);
    bin[p] = ((u32)(s & 127) << 17) | (u32)d;
  }
  const int lo2 = b * CHC, hi2 = min(lo2 + CHC, ECT);
  for (int i = lo2 + t; i < hi2; i += 256) {
    const int s = ect_s[i], d = ect_d[i];
    const int p = atomicAdd(&cur[2 * NBK + (d >> 7)], 1);
    bin[p] = ((u32)(d & 127) << 17) | (u32)s;
  }
}

__global__ __launch_bounds__(256) void bucket_fill_kernel(const int* __restrict__ scanned,
    const u32* __restrict__ bin, int* __restrict__ offs, int* __restrict__ big_el)
{
  const int rel = blockIdx.x / NBK;
  const int bucket = blockIdx.x - rel * NBK;
  const int t = threadIdx.x;
  __shared__ int s_cnt[128], s_exc[128], s_cur[128];
  if (t < 128) s_cnt[t] = 0;
  __syncthreads();
  const int base = scanned[(size_t)blockIdx.x * NBLK];
  const int nxt = (blockIdx.x == 3 * NBK - 1) ? (2 * ETT + ECT)
                                              : scanned[((size_t)blockIdx.x + 1) * NBLK];
  const int size = nxt - base;
  for (int i = t; i < size; i += 256)
    atomicAdd(&s_cnt[bin[base + i] >> 17], 1);
  __syncthreads();
  if (t < 128) s_exc[t] = s_cnt[t];
  __syncthreads();
  for (int d = 1; d < 128; d <<= 1) {
    int v = 0;
    if (t < 128 && t >= d) v = s_exc[t - d];
    __syncthreads();
    if (t < 128) s_exc[t] += v;
    __syncthreads();
  }
  const int relbase = rel * ETT;
  const int obase = base - relbase;
  int* off_rel = offs + (size_t)rel * OFFS;
  const int node0 = bucket * 128;
  if (t < 128) {
    const int excl = s_exc[t] - s_cnt[t];
    s_cur[t] = obase + excl;
    if (node0 + t < NT) off_rel[node0 + t] = obase + excl;
  }
  if (t == 0 && bucket == NBK - 1) off_rel[NT] = obase + size;
  __syncthreads();
  int* el_rel = big_el + relbase;
  for (int i = t; i < size; i += 256) {
    const u32 e = bin[base + i];
    const int pos = atomicAdd(&s_cur[e >> 17], 1);
    el_rel[pos] = (int)(e & 0x1FFFFu);
  }
}

// ---------- K5: fused 3-relation gather; 16-lane group per dst, 8 ch/lane ----------
// 4-edge unrolled, consume-then-reload software pipeline (no register rotation):
//   pair A holds edges k,k+1; pair B holds k+2,k+3; edge indices for the NEXT
//   iteration (tp0..tp3) were loaded one full iteration ahead, so row/logit
//   loads are issued ~one iteration before their use. Invalid tail slots are
//   handled by zeroing ex (cndmask), not branching. Logits are pre-scaled by
//   log2(e) upstream, so exp2f maps straight to v_exp_f32.
__device__ __forceinline__ void acc8(float ex, uint4 p, float* __restrict__ a) {
  a[0] = fmaf(ex, lof(p.x), a[0]); a[1] = fmaf(ex, hif(p.x), a[1]);
  a[2] = fmaf(ex, lof(p.y), a[2]); a[3] = fmaf(ex, hif(p.y), a[3]);
  a[4] = fmaf(ex, lof(p.z), a[4]); a[5] = fmaf(ex, hif(p.z), a[5]);
  a[6] = fmaf(ex, lof(p.w), a[6]); a[7] = fmaf(ex, hif(p.w), a[7]);
}

__device__ __forceinline__ void gat_pipe16(const int* __restrict__ off,
    const int* __restrict__ el, const float* __restrict__ aS, const float* __restrict__ aD,
    const u16* __restrict__ hb, int d, int h, int lg, int self_loop, float w,
    float* __restrict__ acc)
{
  const int beg = off[d];
  const int m = off[d + 1] - beg;     // real edges
  const int cnt = m + self_loop;
  if (cnt <= 0) return;
  const float ad = aD[(u32)d * 4u + (u32)h];
  const uint4* __restrict__ hb4 = (const uint4*)hb;
  const u32 lgo = (u32)lg;
  float den = 0.f;
  float a[8];
#pragma unroll
  for (int i = 0; i < 8; ++i) a[i] = 0.f;
  // preamble: slots 0..3 into pairs A,B; slots 4..7 indices into tp
  const int sA0 = (0 < m) ? el[beg + 0] : d;
  const int sA1 = (1 < m) ? el[beg + 1] : d;
  const int sB0 = (2 < m) ? el[beg + 2] : d;
  const int sB1 = (3 < m) ? el[beg + 3] : d;
  float eA0 = aS[(u32)sA0 * 4u + (u32)h];
  float eA1 = aS[(u32)sA1 * 4u + (u32)h];
  uint4 pA0 = hb4[(u32)sA0 * 16u + lgo];
  uint4 pA1 = hb4[(u32)sA1 * 16u + lgo];
  float eB0 = aS[(u32)sB0 * 4u + (u32)h];
  float eB1 = aS[(u32)sB1 * 4u + (u32)h];
  uint4 pB0 = hb4[(u32)sB0 * 16u + lgo];
  uint4 pB1 = hb4[(u32)sB1 * 16u + lgo];
  int tp0 = (4 < m) ? el[beg + 4] : d;
  int tp1 = (5 < m) ? el[beg + 5] : d;
  int tp2 = (6 < m) ? el[beg + 6] : d;
  int tp3 = (7 < m) ? el[beg + 7] : d;
#pragma unroll 1
  for (int k = 0; k < cnt; k += 4) {
    // process pair A (slots k, k+1); slot k is always valid
    {
      float x0 = eA0 + ad; x0 = fmaxf(x0, SLOPE * x0);
      float x1 = eA1 + ad; x1 = fmaxf(x1, SLOPE * x1);
      const float ex0 = exp2f(x0);
      const float ex1 = (k + 1 < cnt) ? exp2f(x1) : 0.f;
      den += ex0 + ex1;
      acc8(ex0, pA0, a);
      acc8(ex1, pA1, a);
    }
    // reload pair A with slots k+4, k+5 (indices prefetched last iteration)
    eA0 = aS[(u32)tp0 * 4u + (u32)h];
    eA1 = aS[(u32)tp1 * 4u + (u32)h];
    pA0 = hb4[(u32)tp0 * 16u + lgo];
    pA1 = hb4[(u32)tp1 * 16u + lgo];
    // process pair B (slots k+2, k+3)
    {
      float x0 = eB0 + ad; x0 = fmaxf(x0, SLOPE * x0);
      float x1 = eB1 + ad; x1 = fmaxf(x1, SLOPE * x1);
      const float ex0 = (k + 2 < cnt) ? exp2f(x0) : 0.f;
      const float ex1 = (k + 3 < cnt) ? exp2f(x1) : 0.f;
      den += ex0 + ex1;
      acc8(ex0, pB0, a);
      acc8(ex1, pB1, a);
    }
    // reload pair B with slots k+6, k+7
    eB0 = aS[(u32)tp2 * 4u + (u32)h];
    eB1 = aS[(u32)tp3 * 4u + (u32)h];
    pB0 = hb4[(u32)tp2 * 16u + lgo];
    pB1 = hb4[(u32)tp3 * 16u + lgo];
    // prefetch indices for next iteration (slots k+8..k+11)
    tp0 = (k + 8 < m) ? el[beg + k + 8] : d;
    tp1 = (k + 9 < m) ? el[beg + k + 9] : d;
    tp2 = (k + 10 < m) ? el[beg + k + 10] : d;
    tp3 = (k + 11 < m) ? el[beg + k + 11] : d;
  }
  const float s = w / den;            // den > 0 since slot 0 always valid
#pragma unroll
  for (int i = 0; i < 8; ++i) acc[i] = fmaf(a[i], s, acc[i]);
}

__global__ __launch_bounds__(256) void gather_all_kernel(
    const int* __restrict__ off_f, const int* __restrict__ el_f,
    const float* __restrict__ aS_sd, const float* __restrict__ aD_sd, const u16* __restrict__ hs,
    const int* __restrict__ off_r, const int* __restrict__ el_r,
    const float* __restrict__ aS_ds, const float* __restrict__ aD_ds, const u16* __restrict__ hd,
    const int* __restrict__ off_c, const int* __restrict__ el_c,
    const float* __restrict__ aS_ct, const float* __restrict__ aD_ct, const u16* __restrict__ hc,
    const u16* __restrict__ skip, const float* __restrict__ cbias, u16* __restrict__ x)
{
  const int d = blockIdx.x * 16 + (threadIdx.x >> 4);
  if (d >= NT) return;
  const int lg = threadIdx.x & 15;    // lane in group
  const int h = lg >> 2;              // head for this lane's channels
  const int cb = lg * 8;              // channel base (8 channels per lane)
  float acc[8];
  for (int i = 0; i < 8; ++i) acc[i] = 0.f;
  gat_pipe16(off_f, el_f, aS_sd, aD_sd, hs, d, h, lg, 1, 0.25f, acc);
  gat_pipe16(off_r, el_r, aS_ds, aD_ds, hd, d, h, lg, 1, 0.25f, acc);
  gat_pipe16(off_c, el_c, aS_ct, aD_ct, hc, d, h, lg, 0, 0.5f, acc);
  const uint4 sk = *(const uint4*)(skip + (size_t)d * 128 + cb);
  const float4 cb0 = *(const float4*)(cbias + cb);
  const float4 cb1 = *(const float4*)(cbias + cb + 4);
  const float o0 = fmaxf(acc[0] + cb0.x + lof(sk.x), 0.f);
  const float o1 = fmaxf(acc[1] + cb0.y + hif(sk.x), 0.f);
  const float o2 = fmaxf(acc[2] + cb0.z + lof(sk.y), 0.f);
  const float o3 = fmaxf(acc[3] + cb0.w + hif(sk.y), 0.f);
  const float o4 = fmaxf(acc[4] + cb1.x + lof(sk.z), 0.f);
  const float o5 = fmaxf(acc[5] + cb1.y + hif(sk.z), 0.f);
  const float o6 = fmaxf(acc[6] + cb1.z + lof(sk.w), 0.f);
  const float o7 = fmaxf(acc[7] + cb1.w + hif(sk.w), 0.f);
  uint4 r;
  r.x = (u32)f2bf(o0) | ((u32)f2bf(o1) << 16);
  r.y = (u32)f2bf(o2) | ((u32)f2bf(o3) << 16);
  r.z = (u32)f2bf(o4) | ((u32)f2bf(o5) << 16);
  r.w = (u32)f2bf(o6) | ((u32)f2bf(o7) << 16);
  *(uint4*)(x + (size_t)d * 128 + cb) = r;
}

extern "C" void kernel_launch(void* const* d_in, const int* in_sizes, int n_in,
                              void* d_out, int out_size, void* d_ws, size_t ws_size,
                              hipStream_t stream)
{
  const float* x_t   = (const float*)d_in[0];
  const float* x_c   = (const float*)d_in[1];
  const int*   e_tt  = (const int*)d_in[2];
  const int*   ect_s = (const int*)d_in[3];
  const int*   ect_d = (const int*)d_in[4];
  const float* Wpt = (const float*)d_in[5];   const float* bpt = (const float*)d_in[6];
  const float* Wpc = (const float*)d_in[7];   const float* bpc = (const float*)d_in[8];
  const float* Wsd = (const float*)d_in[9];   const float* As_sd = (const float*)d_in[10];
  const float* Ad_sd = (const float*)d_in[11]; const float* bsd = (const float*)d_in[12];
  const float* Wds = (const float*)d_in[13];  const float* As_ds = (const float*)d_in[14];
  const float* Ad_ds = (const float*)d_in[15]; const float* bds = (const float*)d_in[16];
  const float* Wcs = (const float*)d_in[17];  const float* Wcd = (const float*)d_in[18];
  const float* As_ct = (const float*)d_in[19]; const float* Ad_ct = (const float*)d_in[20];
  const float* bct = (const float*)d_in[21];
  const float* Wout = (const float*)d_in[22]; const float* bout = (const float*)d_in[23];

  // workspace (~140 MB)
  char* p = (char*)d_ws;
  size_t off = 0;
  auto alloc = [&](size_t bytes) { char* r = p + off; off += (bytes + 255) & ~(size_t)255; return r; };
  u16* ht_bf   = (u16*)alloc((size_t)NT * 128 * 2);
  u16* hs_bf   = (u16*)alloc((size_t)NT * 128 * 2);
  u16* hd_bf   = (u16*)alloc((size_t)NT * 128 * 2);
  u16* hc_bf   = (u16*)alloc((size_t)NC * 128 * 2);
  u16* x_bf    = (u16*)alloc((size_t)NT * 128 * 2);
  float* aS_sd = (float*)alloc((size_t)NT * 4 * 4);
  float* aD_sd = (float*)alloc((size_t)NT * 4 * 4);
  float* aS_ds = (float*)alloc((size_t)NT * 4 * 4);
  float* aD_ds = (float*)alloc((size_t)NT * 4 * 4);
  float* aS_ct = (float*)alloc((size_t)NC * 4 * 4);
  float* aD_ct = (float*)alloc((size_t)NT * 4 * 4);
  int* cntblk  = (int*)alloc((size_t)TOTC * 4);
  int* scanned = (int*)alloc((size_t)TOTC * 4);
  u32* bin     = (u32*)alloc((size_t)(2 * ETT + ECT) * 4);
  int* big_el  = (int*)alloc((size_t)(2 * ETT + ECT) * 4);
  int* offs    = (int*)alloc((size_t)3 * OFFS * 4);
  int* bsum    = (int*)alloc((size_t)NSB * 4);
  int* bpre    = (int*)alloc((size_t)NSB * 4);
  float* fold_cd = (float*)alloc(512 * 4);
  float* cbias   = (float*)alloc(128 * 4);
  u16* bfrag_sd  = (u16*)alloc((size_t)9 * 4 * 64 * 8 * 2);
  u16* bfrag_ds  = (u16*)alloc((size_t)9 * 4 * 64 * 8 * 2);
  u16* bfrag_out = (u16*)alloc((size_t)8 * 4 * 64 * 8 * 2);

  int* off_f = offs;
  int* off_r = offs + OFFS;
  int* off_c = offs + 2 * OFFS;
  int* el_f = big_el;
  int* el_r = big_el + ETT;
  int* el_c = big_el + 2 * ETT;

  const int* tt_src = e_tt;
  const int* tt_dst = e_tt + ETT;

  const int gT = (NT + 31) / 32;       // 3125
  const int gC = (NC + 31) / 32;       // 782
  const int gM = (NT + 63) / 64;       // 1563 (MFMA blocks)

  // CSR build (bucket-binned counting sort, no global atomics)
  hist_blk_kernel<<<NBLK, 256, 0, stream>>>(tt_src, tt_dst, ect_d, cntblk);
  scan2_blk_kernel<<<NSB, 256, 0, stream>>>(cntblk, scanned, bsum);
  scan2_top_kernel<<<1, 512, 0, stream>>>(bsum, bpre);
  scan2_add_kernel<<<NSB, 256, 0, stream>>>(bpre, scanned);
  bin_kernel<<<NBLK, 256, 0, stream>>>(tt_src, tt_dst, ect_s, ect_d, scanned, bin);
  bucket_fill_kernel<<<3 * NBK, 256, 0, stream>>>(scanned, bin, offs, big_el);

  // weight prep: MFMA frag layouts + fold_cd + cbias (4 blocks)
  prep_kernel<<<4, 256, 0, stream>>>(Wsd, As_sd, Ad_sd, Wds, As_ds, Ad_ds, Wout,
                                     bfrag_sd, bfrag_ds, bfrag_out,
                                     Wcd, Ad_ct, bsd, bds, bct, fold_cd, cbias);

  // node transforms
  pre_t_kernel<<<gT, 256, 0, stream>>>(x_t, Wpt, bpt, fold_cd, ht_bf, aD_ct, NT);
  mfma_logits2_kernel<<<gM, 256, 0, stream>>>((const short*)ht_bf,
      (const short*)bfrag_sd, (const short*)bfrag_ds,
      hs_bf, aS_sd, aD_sd, hd_bf, aS_ds, aD_ds, NT);
  ctx_kernel<<<gC, 256, 0, stream>>>(x_c, Wpc, bpc, Wcs, As_ct, hc_bf, aS_ct, NC);

  // fused gather (sd + ds + ct + cbias + skip + relu) -> x_bf
  gather_all_kernel<<<(NT + 15) / 16, 256, 0, stream>>>(
      off_f, el_f, aS_sd, aD_sd, hs_bf,
      off_r, el_r, aS_ds, aD_ds, hd_bf,
      off_c, el_c, aS_ct, aD_ct, hc_bf,
      ht_bf, cbias, x_bf);

  // final MFMA GEMM -> d_out (fp32)
  mfma_out_kernel<<<gM, 256, 0, stream>>>((const short*)x_bf, (const short*)bfrag_out,
                                          bout, (float*)d_out, NT);
}

// Round 3
// 434.374 us; speedup vs baseline: 1.0245x; 1.0245x over previous
//
#include <hip/hip_runtime.h>
#include <cstdint>
#include <cstddef>

typedef unsigned short u16;
typedef unsigned int u32;

#define NT 100000
#define NC 25000
#define ETT 800000
#define ECT 400000
#define SLOPE 0.2f
#define LOG2E 1.4426950408889634f
#define OFFS (NT + 4)           // padded stride for offset arrays (16B-aligned)

// bucket-binned CSR build
#define NBK 782                 // ceil(NT/128) buckets of 128 nodes
#define NBLK 256                // binning blocks
#define CHT ((ETT + NBLK - 1) / NBLK)   // 3125 tt edges / block
#define CHC ((ECT + NBLK - 1) / NBLK)   // 1563 ct edges / block
#define TOTC (3 * NBK * NBLK)           // 600576 counts
#define NSB ((TOTC + 2047) / 2048)      // 294 scan blocks

typedef __attribute__((ext_vector_type(8))) short bf16x8;
typedef __attribute__((ext_vector_type(4))) float f32x4;

__device__ __forceinline__ u16 f2bf(float f) {
  u32 u = __float_as_uint(f);
  u32 r = (u >> 16) & 1u;
  return (u16)((u + 0x7fffu + r) >> 16);
}
__device__ __forceinline__ float lof(u32 p) { return __uint_as_float(p << 16); }
__device__ __forceinline__ float hif(u32 p) { return __uint_as_float(p & 0xffff0000u); }

// ---------- K1: h_t(bf16) = relu(x_t @ Wpt + b); aD_ct = relu(h_t) @ fold_cd ----------
__global__ __launch_bounds__(256) void pre_t_kernel(const float* __restrict__ in,
    const float* __restrict__ W, const float* __restrict__ bias,
    const float* __restrict__ fold_cd, u16* __restrict__ h_t,
    float* __restrict__ aD, int N)
{
  __shared__ float s_in[32][33];
  __shared__ float s_W[32][128];
  __shared__ float s_fold[512];
  const int t = threadIdx.x;
  s_fold[t] = fold_cd[t];
  s_fold[t + 256] = fold_cd[t + 256];
  const int row0 = blockIdx.x * 32;
  const int rl = t >> 3, cg = t & 7;
  const int gr = row0 + rl;
  float acc[4][4];
  for (int g = 0; g < 4; ++g)
    for (int j = 0; j < 4; ++j)
      acc[g][j] = bias[g * 32 + cg * 4 + j];
  for (int kc = 0; kc < 64; kc += 32) {
    {
      float4 f = make_float4(0.f, 0.f, 0.f, 0.f);
      if (gr < N) f = *(const float4*)(in + (size_t)gr * 64 + kc + cg * 4);
      s_in[rl][cg * 4 + 0] = f.x; s_in[rl][cg * 4 + 1] = f.y;
      s_in[rl][cg * 4 + 2] = f.z; s_in[rl][cg * 4 + 3] = f.w;
    }
    for (int j = 0; j < 4; ++j) {
      const int idx = t + j * 256;
      const int k = idx >> 5, c4 = (idx & 31) * 4;
      *(float4*)&s_W[k][c4] = *(const float4*)(W + (size_t)(kc + k) * 128 + c4);
    }
    __syncthreads();
#pragma unroll 8
    for (int k = 0; k < 32; ++k) {
      const float a = s_in[rl][k];
      for (int g = 0; g < 4; ++g) {
        const float4 w = *(const float4*)&s_W[k][g * 32 + cg * 4];
        acc[g][0] = fmaf(a, w.x, acc[g][0]);
        acc[g][1] = fmaf(a, w.y, acc[g][1]);
        acc[g][2] = fmaf(a, w.z, acc[g][2]);
        acc[g][3] = fmaf(a, w.w, acc[g][3]);
      }
    }
    __syncthreads();
  }
  if (gr < N) {
    float p0 = 0.f, p1 = 0.f, p2 = 0.f, p3 = 0.f;
    for (int g = 0; g < 4; ++g) {
      for (int j = 0; j < 4; ++j) acc[g][j] = fmaxf(acc[g][j], 0.f);
      uint2 pk;
      pk.x = (u32)f2bf(acc[g][0]) | ((u32)f2bf(acc[g][1]) << 16);
      pk.y = (u32)f2bf(acc[g][2]) | ((u32)f2bf(acc[g][3]) << 16);
      *(uint2*)(h_t + (size_t)gr * 128 + g * 32 + cg * 4) = pk;
      for (int j = 0; j < 4; ++j) {
        const int col = g * 32 + cg * 4 + j;
        const float4 f4 = *(const float4*)&s_fold[col * 4];
        const float a = acc[g][j];
        p0 = fmaf(a, f4.x, p0); p1 = fmaf(a, f4.y, p1);
        p2 = fmaf(a, f4.z, p2); p3 = fmaf(a, f4.w, p3);
      }
    }
    for (int m = 1; m < 8; m <<= 1) {
      p0 += __shfl_xor(p0, m); p1 += __shfl_xor(p1, m);
      p2 += __shfl_xor(p2, m); p3 += __shfl_xor(p3, m);
    }
    if (cg == 0) *(float4*)(aD + (size_t)gr * 4) = make_float4(p0, p1, p2, p3);
  }
}

// ---------- weight prep: frag-linear bf16 B for MFMA (+ fold cols) + fold_cd + cbias ----------
// NOTE: attention-fold columns (fS/fD/fold_cd) are pre-scaled by log2(e) so the
// gather kernel can use native exp2 (LeakyReLU is positively homogeneous).
__global__ __launch_bounds__(256) void prep_kernel(
    const float* __restrict__ Wsd, const float* __restrict__ AsSd, const float* __restrict__ AdSd,
    const float* __restrict__ Wds, const float* __restrict__ AsDs, const float* __restrict__ AdDs,
    const float* __restrict__ Wout, u16* __restrict__ bf_sd, u16* __restrict__ bf_ds,
    u16* __restrict__ bf_out,
    const float* __restrict__ Wcd, const float* __restrict__ attD,
    const float* __restrict__ bsd, const float* __restrict__ bds, const float* __restrict__ bct,
    float* __restrict__ fold_cd, float* __restrict__ cbias)
{
  const int b = blockIdx.x;
  const int tid = threadIdx.x;
  if (b == 3) {
    if (tid < 128) {
      for (int h = 0; h < 4; ++h) {
        float s = 0.f;
        for (int c = 0; c < 32; ++c)
          s = fmaf(Wcd[tid * 128 + h * 32 + c], attD[h * 32 + c], s);
        fold_cd[tid * 4 + h] = s * LOG2E;
      }
      cbias[tid] = 0.25f * bsd[tid] + 0.25f * bds[tid] + 0.5f * bct[tid];
    }
    return;
  }
  __shared__ float fS[512], fD[512];
  const float* W = (b == 0) ? Wsd : (b == 1) ? Wds : Wout;
  const float* As = (b == 0) ? AsSd : AsDs;
  const float* Ad = (b == 0) ? AdSd : AdDs;
  u16* out = (b == 0) ? bf_sd : (b == 1) ? bf_ds : bf_out;
  const int tiles = (b == 2) ? 8 : 9;
  if (b < 2) {
    if (tid < 128) {
      for (int h = 0; h < 4; ++h) {
        float s1 = 0.f, s2 = 0.f;
        for (int c = 0; c < 32; ++c) {
          const float wv = W[tid * 128 + h * 32 + c];
          s1 = fmaf(wv, As[h * 32 + c], s1);
          s2 = fmaf(wv, Ad[h * 32 + c], s2);
        }
        fS[tid * 4 + h] = s1 * LOG2E; fD[tid * 4 + h] = s2 * LOG2E;
      }
    }
    __syncthreads();
  }
  const int total = tiles * 4 * 64 * 8;
  for (int i = tid; i < total; i += 256) {
    const int j = i & 7, lane = (i >> 3) & 63, ks = (i >> 9) & 3, t = i >> 11;
    const int k = ks * 32 + (lane >> 4) * 8 + j;
    const int n = t * 16 + (lane & 15);
    float v;
    if (n < 128) v = W[k * 128 + n];
    else if (n < 132) v = fS[k * 4 + (n - 128)];
    else if (n < 136) v = fD[k * 4 + (n - 132)];
    else v = 0.f;
    out[i] = f2bf(v);
  }
}

// ---------- fused MFMA GEMM x2 (sd + ds), N=144 each: bf16 out + aS/aD logits ----------
__global__ __launch_bounds__(256) void mfma_logits2_kernel(
    const short* __restrict__ A, const short* __restrict__ Bsd, const short* __restrict__ Bds,
    u16* __restrict__ hs, float* __restrict__ aSsd, float* __restrict__ aDsd,
    u16* __restrict__ hd, float* __restrict__ aSds, float* __restrict__ aDds, int M)
{
  __shared__ __align__(16) float lds[4][16][148];
  const int wv = threadIdx.x >> 6, lane = threadIdx.x & 63;
  const int quad = lane >> 4, l16 = lane & 15;
  const int row0 = blockIdx.x * 64 + wv * 16;
  const int arow = min(row0 + l16, M - 1);
  const short* ap = A + (size_t)arow * 128 + quad * 8;
  bf16x8 af[4];
  for (int ks = 0; ks < 4; ++ks) af[ks] = *(const bf16x8*)(ap + ks * 32);
  const int row = row0 + l16;
  const int idx = lane & 7, rr = lane >> 3;
  for (int pass = 0; pass < 2; ++pass) {
    const short* B = pass ? Bds : Bsd;
    u16* outb = pass ? hd : hs;
    float* aS = pass ? aSds : aSsd;
    float* aD = pass ? aDds : aDsd;
    f32x4 acc[9];
    for (int t = 0; t < 9; ++t) acc[t] = (f32x4){0.f, 0.f, 0.f, 0.f};
    for (int ks = 0; ks < 4; ++ks)
      for (int t = 0; t < 9; ++t) {
        const bf16x8 bf = *(const bf16x8*)(B + ((t * 4 + ks) * 64 + lane) * 8);
        acc[t] = __builtin_amdgcn_mfma_f32_16x16x32_bf16(af[ks], bf, acc[t], 0, 0, 0);
      }
    for (int t = 0; t < 9; ++t)
      for (int r = 0; r < 4; ++r)
        lds[wv][quad * 4 + r][t * 16 + l16] = acc[t][r];
    __syncthreads();
    if (row < M) {
      for (int g = 0; g < 8; ++g) {
        const f32x4 v = *(const f32x4*)&lds[wv][l16][g * 16 + quad * 4];
        uint2 pk;
        pk.x = (u32)f2bf(v[0]) | ((u32)f2bf(v[1]) << 16);
        pk.y = (u32)f2bf(v[2]) | ((u32)f2bf(v[3]) << 16);
        *(uint2*)(outb + (size_t)row * 128 + g * 16 + quad * 4) = pk;
      }
    }
    for (int p = 0; p < 2; ++p) {
      const int lr = p * 8 + rr;
      const int n = row0 + lr;
      if (n < M) {
        const float v = lds[wv][lr][128 + idx];
        if (idx < 4) aS[(size_t)n * 4 + idx] = v;
        else aD[(size_t)n * 4 + idx - 4] = v;
      }
    }
    __syncthreads();
  }
}

// ---------- MFMA GEMM, N=128 (8 tiles) + bias -> fp32 out ----------
__global__ __launch_bounds__(256) void mfma_out_kernel(
    const short* __restrict__ A, const short* __restrict__ B,
    const float* __restrict__ bias, float* __restrict__ out, int M)
{
  __shared__ __align__(16) float lds[4][16][132];
  const int wv = threadIdx.x >> 6, lane = threadIdx.x & 63;
  const int quad = lane >> 4, l16 = lane & 15;
  const int row0 = blockIdx.x * 64 + wv * 16;
  const int arow = min(row0 + l16, M - 1);
  const short* ap = A + (size_t)arow * 128 + quad * 8;
  bf16x8 af[4];
  for (int ks = 0; ks < 4; ++ks) af[ks] = *(const bf16x8*)(ap + ks * 32);
  f32x4 acc[8];
  for (int t = 0; t < 8; ++t) acc[t] = (f32x4){0.f, 0.f, 0.f, 0.f};
  for (int ks = 0; ks < 4; ++ks)
    for (int t = 0; t < 8; ++t) {
      const bf16x8 bf = *(const bf16x8*)(B + ((t * 4 + ks) * 64 + lane) * 8);
      acc[t] = __builtin_amdgcn_mfma_f32_16x16x32_bf16(af[ks], bf, acc[t], 0, 0, 0);
    }
  for (int t = 0; t < 8; ++t)
    for (int r = 0; r < 4; ++r)
      lds[wv][quad * 4 + r][t * 16 + l16] = acc[t][r];
  __syncthreads();
  const int row = row0 + l16;
  if (row < M) {
    for (int g = 0; g < 8; ++g) {
      const int col = g * 16 + quad * 4;
      f32x4 v = *(const f32x4*)&lds[wv][l16][col];
      const f32x4 b4 = *(const f32x4*)(bias + col);
      v = v + b4;
      *(f32x4*)(out + (size_t)row * 128 + col) = v;
    }
  }
}

// ---------- K4: hcs = relu(x_c @ Wpc + b) @ Wcs (bf16) + a_s_ct ----------
__global__ __launch_bounds__(256) void ctx_kernel(const float* __restrict__ x_c,
    const float* __restrict__ Wpc, const float* __restrict__ bpc,
    const float* __restrict__ Wcs, const float* __restrict__ attS,
    u16* __restrict__ hc_bf, float* __restrict__ aS, int N)
{
  __shared__ float s_in[32][33];
  __shared__ float s_W[32][128];
  __shared__ float s_h[32][132];
  const int t = threadIdx.x;
  const int row0 = blockIdx.x * 32;
  const int rl = t >> 3, cg = t & 7;
  const int gr = row0 + rl;
  {
    float4 f = make_float4(0.f, 0.f, 0.f, 0.f);
    if (gr < N) f = *(const float4*)(x_c + (size_t)gr * 32 + cg * 4);
    s_in[rl][cg * 4 + 0] = f.x; s_in[rl][cg * 4 + 1] = f.y;
    s_in[rl][cg * 4 + 2] = f.z; s_in[rl][cg * 4 + 3] = f.w;
  }
  for (int j = 0; j < 4; ++j) {
    const int idx = t + j * 256;
    const int k = idx >> 5, c4 = (idx & 31) * 4;
    *(float4*)&s_W[k][c4] = *(const float4*)(Wpc + (size_t)k * 128 + c4);
  }
  __syncthreads();
  float acc[4][4];
  for (int g = 0; g < 4; ++g)
    for (int j = 0; j < 4; ++j) acc[g][j] = bpc[g * 32 + cg * 4 + j];
#pragma unroll 8
  for (int k = 0; k < 32; ++k) {
    const float a = s_in[rl][k];
    for (int g = 0; g < 4; ++g) {
      const float4 w = *(const float4*)&s_W[k][g * 32 + cg * 4];
      acc[g][0] = fmaf(a, w.x, acc[g][0]);
      acc[g][1] = fmaf(a, w.y, acc[g][1]);
      acc[g][2] = fmaf(a, w.z, acc[g][2]);
      acc[g][3] = fmaf(a, w.w, acc[g][3]);
    }
  }
  for (int g = 0; g < 4; ++g)
    *(float4*)&s_h[rl][g * 32 + cg * 4] =
        make_float4(fmaxf(acc[g][0], 0.f), fmaxf(acc[g][1], 0.f),
                    fmaxf(acc[g][2], 0.f), fmaxf(acc[g][3], 0.f));
  __syncthreads();
  float acc2[4][4];
  for (int g = 0; g < 4; ++g)
    for (int j = 0; j < 4; ++j) acc2[g][j] = 0.f;
  for (int kc = 0; kc < 128; kc += 32) {
    for (int j = 0; j < 4; ++j) {
      const int idx = t + j * 256;
      const int k = idx >> 5, c4 = (idx & 31) * 4;
      *(float4*)&s_W[k][c4] = *(const float4*)(Wcs + (size_t)(kc + k) * 128 + c4);
    }
    __syncthreads();
#pragma unroll 8
    for (int k = 0; k < 32; ++k) {
      const float a = s_h[rl][kc + k];
      for (int g = 0; g < 4; ++g) {
        const float4 w = *(const float4*)&s_W[k][g * 32 + cg * 4];
        acc2[g][0] = fmaf(a, w.x, acc2[g][0]);
        acc2[g][1] = fmaf(a, w.y, acc2[g][1]);
        acc2[g][2] = fmaf(a, w.z, acc2[g][2]);
        acc2[g][3] = fmaf(a, w.w, acc2[g][3]);
      }
    }
    __syncthreads();
  }
  if (gr < N) {
    float pS[4];
    for (int g = 0; g < 4; ++g) {
      uint2 pk;
      pk.x = (u32)f2bf(acc2[g][0]) | ((u32)f2bf(acc2[g][1]) << 16);
      pk.y = (u32)f2bf(acc2[g][2]) | ((u32)f2bf(acc2[g][3]) << 16);
      *(uint2*)(hc_bf + (size_t)gr * 128 + g * 32 + cg * 4) = pk;
      const float4 as4 = *(const float4*)(attS + g * 32 + cg * 4);
      pS[g] = acc2[g][0] * as4.x + acc2[g][1] * as4.y + acc2[g][2] * as4.z + acc2[g][3] * as4.w;
    }
    for (int m = 1; m < 8; m <<= 1)
      for (int g = 0; g < 4; ++g) pS[g] += __shfl_xor(pS[g], m);
    if (cg == 0)
      *(float4*)(aS + (size_t)gr * 4) =
          make_float4(pS[0] * LOG2E, pS[1] * LOG2E, pS[2] * LOG2E, pS[3] * LOG2E);
  }
}

// ---------- bucket-binned CSR build (no global atomics) ----------
__global__ __launch_bounds__(256) void hist_blk_kernel(const int* __restrict__ tt_src,
    const int* __restrict__ tt_dst, const int* __restrict__ ect_d, int* __restrict__ cntblk)
{
  __shared__ int h[3 * NBK];
  const int t = threadIdx.x, b = blockIdx.x;
  for (int i = t; i < 3 * NBK; i += 256) h[i] = 0;
  __syncthreads();
  const int lo = b * CHT, hi = min(lo + CHT, ETT);
  for (int i = lo + t; i < hi; i += 256) {
    atomicAdd(&h[tt_dst[i] >> 7], 1);
    atomicAdd(&h[NBK + (tt_src[i] >> 7)], 1);
  }
  const int lo2 = b * CHC, hi2 = min(lo2 + CHC, ECT);
  for (int i = lo2 + t; i < hi2; i += 256)
    atomicAdd(&h[2 * NBK + (ect_d[i] >> 7)], 1);
  __syncthreads();
  for (int i = t; i < 3 * NBK; i += 256)
    cntblk[(size_t)i * NBLK + b] = h[i];
}

__global__ __launch_bounds__(256) void scan2_blk_kernel(const int* __restrict__ in,
    int* __restrict__ out, int* __restrict__ bsum)
{
  const int t = threadIdx.x, b = blockIdx.x;
  const int idx = b * 2048 + t * 8;
  int v[8];
  int s = 0;
  if (idx < TOTC) {
    const int4 q0 = *(const int4*)(in + idx);
    const int4 q1 = *(const int4*)(in + idx + 4);
    int x;
    x = q0.x; v[0] = s; s += x;  x = q0.y; v[1] = s; s += x;
    x = q0.z; v[2] = s; s += x;  x = q0.w; v[3] = s; s += x;
    x = q1.x; v[4] = s; s += x;  x = q1.y; v[5] = s; s += x;
    x = q1.z; v[6] = s; s += x;  x = q1.w; v[7] = s; s += x;
  } else {
    for (int j = 0; j < 8; ++j) v[j] = 0;
  }
  __shared__ int sh[256];
  sh[t] = s;
  __syncthreads();
  for (int d = 1; d < 256; d <<= 1) {
    const int u = (t >= d) ? sh[t - d] : 0;
    __syncthreads();
    sh[t] += u;
    __syncthreads();
  }
  const int excl = (t == 0) ? 0 : sh[t - 1];
  if (idx < TOTC) {
    int4 q0, q1;
    q0.x = excl + v[0]; q0.y = excl + v[1]; q0.z = excl + v[2]; q0.w = excl + v[3];
    q1.x = excl + v[4]; q1.y = excl + v[5]; q1.z = excl + v[6]; q1.w = excl + v[7];
    *(int4*)(out + idx) = q0;
    *(int4*)(out + idx + 4) = q1;
  }
  if (t == 255) bsum[b] = sh[255];
}

__global__ __launch_bounds__(512) void scan2_top_kernel(const int* __restrict__ bsum,
    int* __restrict__ bpre)
{
  __shared__ int sh[512];
  const int t = threadIdx.x;
  const int orig = (t < NSB) ? bsum[t] : 0;
  sh[t] = orig;
  __syncthreads();
  for (int d = 1; d < 512; d <<= 1) {
    const int v = (t >= d) ? sh[t - d] : 0;
    __syncthreads();
    sh[t] += v;
    __syncthreads();
  }
  if (t < NSB) bpre[t] = sh[t] - orig;
}

__global__ __launch_bounds__(256) void scan2_add_kernel(const int* __restrict__ bpre,
    int* __restrict__ out)
{
  const int t = threadIdx.x, b = blockIdx.x;
  const int bp = bpre[b];
  const int idx = b * 2048 + t * 8;
  if (idx < TOTC) {
    int4 q0 = *(const int4*)(out + idx);
    int4 q1 = *(const int4*)(out + idx + 4);
    q0.x += bp; q0.y += bp; q0.z += bp; q0.w += bp;
    q1.x += bp; q1.y += bp; q1.z += bp; q1.w += bp;
    *(int4*)(out + idx) = q0;
    *(int4*)(out + idx + 4) = q1;
  }
}

__global__ __launch_bounds__(256) void bin_kernel(const int* __restrict__ tt_src,
    const int* __restrict__ tt_dst, const int* __restrict__ ect_s, const int* __restrict__ ect_d,
    const int* __restrict__ scanned, u32* __restrict__ bin)
{
  __shared__ int cur[3 * NBK];
  const int t = threadIdx.x, b = blockIdx.x;
  for (int i = t; i < 3 * NBK; i += 256)
    cur[i] = scanned[(size_t)i * NBLK + b];
  __syncthreads();
  const int lo = b * CHT, hi = min(lo + CHT, ETT);
  for (int i = lo + t; i < hi; i += 256) {
    const int s = tt_src[i], d = tt_dst[i];
    int p = atomicAdd(&cur[d >> 7], 1);
    bin[p] = ((u32)(d & 127) << 17) | (u32)s;
    p = atomicAdd(&cur[NBK + (s >> 7)], 1);
    bin[p] = ((u32)(s & 127) << 17) | (u32)d;
  }
  const int lo2 = b * CHC, hi2 = min(lo2 + CHC, ECT);
  for (int i = lo2 + t; i < hi2; i += 256) {
    const int s = ect_s[i], d = ect_d[i];
    const int p = atomicAdd(&cur[2 * NBK + (d >> 7)], 1);
    bin[p] = ((u32)(d & 127) << 17) | (u32)s;
  }
}

__global__ __launch_bounds__(256) void bucket_fill_kernel(const int* __restrict__ scanned,
    const u32* __restrict__ bin, int* __restrict__ offs, int* __restrict__ big_el)
{
  const int rel = blockIdx.x / NBK;
  const int bucket = blockIdx.x - rel * NBK;
  const int t = threadIdx.x;
  __shared__ int s_cnt[128], s_exc[128], s_cur[128];
  if (t < 128) s_cnt[t] = 0;
  __syncthreads();
  const int base = scanned[(size_t)blockIdx.x * NBLK];
  const int nxt = (blockIdx.x == 3 * NBK - 1) ? (2 * ETT + ECT)
                                              : scanned[((size_t)blockIdx.x + 1) * NBLK];
  const int size = nxt - base;
  for (int i = t; i < size; i += 256)
    atomicAdd(&s_cnt[bin[base + i] >> 17], 1);
  __syncthreads();
  if (t < 128) s_exc[t] = s_cnt[t];
  __syncthreads();
  for (int d = 1; d < 128; d <<= 1) {
    int v = 0;
    if (t < 128 && t >= d) v = s_exc[t - d];
    __syncthreads();
    if (t < 128) s_exc[t] += v;
    __syncthreads();
  }
  const int relbase = rel * ETT;
  const int obase = base - relbase;
  int* off_rel = offs + (size_t)rel * OFFS;
  const int node0 = bucket * 128;
  if (t < 128) {
    const int excl = s_exc[t] - s_cnt[t];
    s_cur[t] = obase + excl;
    if (node0 + t < NT) off_rel[node0 + t] = obase + excl;
  }
  if (t == 0 && bucket == NBK - 1) off_rel[NT] = obase + size;
  __syncthreads();
  int* el_rel = big_el + relbase;
  for (int i = t; i < size; i += 256) {
    const u32 e = bin[base + i];
    const int pos = atomicAdd(&s_cur[e >> 17], 1);
    el_rel[pos] = (int)(e & 0x1FFFFu);
  }
}

// ---------- K5: fused 3-relation gather; 16-lane group per dst, 8 ch/lane ----------
// v3: TA-request-minimized pipeline. Per 4-edge iteration the wave now issues
// only 6 vector loads (4 row dwordx4 + 1 aS dword + 1 el dword) instead of 12:
//   - el: lane (lg&3) loads the index for slot k+8+(lg&3); a cross-lane shfl
//     (ds_bpermute, LDS pipe -- not TA) spreads s0..s3 to all lanes.
//   - aS: lane (role=lg>>2, l3=lg&3) loads aS[s_role*4+l3] -- one dword covers
//     all 16 (slot,head) pairs of the group; 4 hoisted-address shfls deliver
//     each lane its per-slot logit contribution.
// Numerics identical to v2 (same clamping to d, same ex-zeroing, same order).
__device__ __forceinline__ void acc8(float ex, uint4 p, float* __restrict__ a) {
  a[0] = fmaf(ex, lof(p.x), a[0]); a[1] = fmaf(ex, hif(p.x), a[1]);
  a[2] = fmaf(ex, lof(p.y), a[2]); a[3] = fmaf(ex, hif(p.y), a[3]);
  a[4] = fmaf(ex, lof(p.z), a[4]); a[5] = fmaf(ex, hif(p.z), a[5]);
  a[6] = fmaf(ex, lof(p.w), a[6]); a[7] = fmaf(ex, hif(p.w), a[7]);
}

__device__ __forceinline__ void gat_pipe16(const int* __restrict__ off,
    const int* __restrict__ el, const float* __restrict__ aS, const float* __restrict__ aD,
    const u16* __restrict__ hb, int d, int h, int lg, int self_loop, float w,
    float* __restrict__ acc)
{
  const int beg = off[d];
  const int m = off[d + 1] - beg;     // real edges
  const int cnt = m + self_loop;
  if (cnt <= 0) return;
  const float ad = aD[(u32)d * 4u + (u32)h];
  const uint4* __restrict__ hb4 = (const uint4*)hb;
  const u32 lgo = (u32)lg;
  const int l3 = lg & 3;              // sub-slot this lane gathers for
  const int role = lg >> 2;           // slot-role this lane gathers aS for
  const int base = (threadIdx.x & ~15);
  // hoisted shfl source lanes (loop-invariant)
  const int sadr0 = base + 0, sadr1 = base + 1, sadr2 = base + 2, sadr3 = base + 3;
  const int aadr0 = base + 0 + h, aadr1 = base + 4 + h;
  const int aadr2 = base + 8 + h, aadr3 = base + 12 + h;
  const int mclamp = (m > 0) ? (m - 1) : 0;
  float den = 0.f;
  float a[8];
#pragma unroll
  for (int i = 0; i < 8; ++i) a[i] = 0.f;
  // preamble: slots 0..3 (scalar per-group broadcast loads, once)
  const int sP0 = (0 < m) ? el[beg + 0] : d;
  const int sP1 = (1 < m) ? el[beg + 1] : d;
  const int sP2 = (2 < m) ? el[beg + 2] : d;
  const int sP3 = (3 < m) ? el[beg + 3] : d;
  uint4 pA0 = hb4[(u32)sP0 * 16u + lgo];
  uint4 pA1 = hb4[(u32)sP1 * 16u + lgo];
  uint4 pB0 = hb4[(u32)sP2 * 16u + lgo];
  uint4 pB1 = hb4[(u32)sP3 * 16u + lgo];
  // aS lane-gather covering slots 0..3
  const int mySP = (role == 0) ? sP0 : (role == 1) ? sP1 : (role == 2) ? sP2 : sP3;
  float asv = aS[(u32)mySP * 4u + (u32)l3];
  // el lane-gather covering slots 4..7
  int elv = el[beg + min(4 + l3, mclamp)];
#pragma unroll 1
  for (int k = 0; k < cnt; k += 4) {
    // logit contributions for slots k..k+3 (from asv, issued 1 iter ago)
    const float eA0 = __shfl(asv, aadr0);
    const float eA1 = __shfl(asv, aadr1);
    const float eB0 = __shfl(asv, aadr2);
    const float eB1 = __shfl(asv, aadr3);
    // source indices for slots k+4..k+7 (from elv, issued 1 iter ago)
    const int jn = k + 4 + l3;
    const int elvf = (jn < m) ? elv : d;
    const int s0 = __shfl(elvf, sadr0);
    const int s1 = __shfl(elvf, sadr1);
    const int s2 = __shfl(elvf, sadr2);
    const int s3 = __shfl(elvf, sadr3);
    // process pair A (slots k, k+1); slot k always valid
    {
      float x0 = eA0 + ad; x0 = fmaxf(x0, SLOPE * x0);
      float x1 = eA1 + ad; x1 = fmaxf(x1, SLOPE * x1);
      const float ex0 = exp2f(x0);
      const float ex1 = (k + 1 < cnt) ? exp2f(x1) : 0.f;
      den += ex0 + ex1;
      acc8(ex0, pA0, a);
      acc8(ex1, pA1, a);
    }
    // reload pair A rows (slots k+4, k+5)
    pA0 = hb4[(u32)s0 * 16u + lgo];
    pA1 = hb4[(u32)s1 * 16u + lgo];
    // process pair B (slots k+2, k+3)
    {
      float x0 = eB0 + ad; x0 = fmaxf(x0, SLOPE * x0);
      float x1 = eB1 + ad; x1 = fmaxf(x1, SLOPE * x1);
      const float ex0 = (k + 2 < cnt) ? exp2f(x0) : 0.f;
      const float ex1 = (k + 3 < cnt) ? exp2f(x1) : 0.f;
      den += ex0 + ex1;
      acc8(ex0, pB0, a);
      acc8(ex1, pB1, a);
    }
    // reload pair B rows (slots k+6, k+7)
    pB0 = hb4[(u32)s2 * 16u + lgo];
    pB1 = hb4[(u32)s3 * 16u + lgo];
    // aS lane-gather for slots k+4..k+7 (consumed next iter)
    const int myS = (role == 0) ? s0 : (role == 1) ? s1 : (role == 2) ? s2 : s3;
    asv = aS[(u32)myS * 4u + (u32)l3];
    // el lane-gather for slots k+8..k+11 (consumed next iter)
    elv = el[beg + min(k + 8 + l3, mclamp)];
  }
  const float s = w / den;            // den > 0 since slot 0 always valid
#pragma unroll
  for (int i = 0; i < 8; ++i) acc[i] = fmaf(a[i], s, acc[i]);
}

__global__ __launch_bounds__(256) void gather_all_kernel(
    const int* __restrict__ off_f, const int* __restrict__ el_f,
    const float* __restrict__ aS_sd, const float* __restrict__ aD_sd, const u16* __restrict__ hs,
    const int* __restrict__ off_r, const int* __restrict__ el_r,
    const float* __restrict__ aS_ds, const float* __restrict__ aD_ds, const u16* __restrict__ hd,
    const int* __restrict__ off_c, const int* __restrict__ el_c,
    const float* __restrict__ aS_ct, const float* __restrict__ aD_ct, const u16* __restrict__ hc,
    const u16* __restrict__ skip, const float* __restrict__ cbias, u16* __restrict__ x)
{
  const int d = blockIdx.x * 16 + (threadIdx.x >> 4);
  if (d >= NT) return;
  const int lg = threadIdx.x & 15;    // lane in group
  const int h = lg >> 2;              // head for this lane's channels
  const int cb = lg * 8;              // channel base (8 channels per lane)
  float acc[8];
  for (int i = 0; i < 8; ++i) acc[i] = 0.f;
  gat_pipe16(off_f, el_f, aS_sd, aD_sd, hs, d, h, lg, 1, 0.25f, acc);
  gat_pipe16(off_r, el_r, aS_ds, aD_ds, hd, d, h, lg, 1, 0.25f, acc);
  gat_pipe16(off_c, el_c, aS_ct, aD_ct, hc, d, h, lg, 0, 0.5f, acc);
  const uint4 sk = *(const uint4*)(skip + (size_t)d * 128 + cb);
  const float4 cb0 = *(const float4*)(cbias + cb);
  const float4 cb1 = *(const float4*)(cbias + cb + 4);
  const float o0 = fmaxf(acc[0] + cb0.x + lof(sk.x), 0.f);
  const float o1 = fmaxf(acc[1] + cb0.y + hif(sk.x), 0.f);
  const float o2 = fmaxf(acc[2] + cb0.z + lof(sk.y), 0.f);
  const float o3 = fmaxf(acc[3] + cb0.w + hif(sk.y), 0.f);
  const float o4 = fmaxf(acc[4] + cb1.x + lof(sk.z), 0.f);
  const float o5 = fmaxf(acc[5] + cb1.y + hif(sk.z), 0.f);
  const float o6 = fmaxf(acc[6] + cb1.z + lof(sk.w), 0.f);
  const float o7 = fmaxf(acc[7] + cb1.w + hif(sk.w), 0.f);
  uint4 r;
  r.x = (u32)f2bf(o0) | ((u32)f2bf(o1) << 16);
  r.y = (u32)f2bf(o2) | ((u32)f2bf(o3) << 16);
  r.z = (u32)f2bf(o4) | ((u32)f2bf(o5) << 16);
  r.w = (u32)f2bf(o6) | ((u32)f2bf(o7) << 16);
  *(uint4*)(x + (size_t)d * 128 + cb) = r;
}

extern "C" void kernel_launch(void* const* d_in, const int* in_sizes, int n_in,
                              void* d_out, int out_size, void* d_ws, size_t ws_size,
                              hipStream_t stream)
{
  const float* x_t   = (const float*)d_in[0];
  const float* x_c   = (const float*)d_in[1];
  const int*   e_tt  = (const int*)d_in[2];
  const int*   ect_s = (const int*)d_in[3];
  const int*   ect_d = (const int*)d_in[4];
  const float* Wpt = (const float*)d_in[5];   const float* bpt = (const float*)d_in[6];
  const float* Wpc = (const float*)d_in[7];   const float* bpc = (const float*)d_in[8];
  const float* Wsd = (const float*)d_in[9];   const float* As_sd = (const float*)d_in[10];
  const float* Ad_sd = (const float*)d_in[11]; const float* bsd = (const float*)d_in[12];
  const float* Wds = (const float*)d_in[13];  const float* As_ds = (const float*)d_in[14];
  const float* Ad_ds = (const float*)d_in[15]; const float* bds = (const float*)d_in[16];
  const float* Wcs = (const float*)d_in[17];  const float* Wcd = (const float*)d_in[18];
  const float* As_ct = (const float*)d_in[19]; const float* Ad_ct = (const float*)d_in[20];
  const float* bct = (const float*)d_in[21];
  const float* Wout = (const float*)d_in[22]; const float* bout = (const float*)d_in[23];

  // workspace (~140 MB)
  char* p = (char*)d_ws;
  size_t off = 0;
  auto alloc = [&](size_t bytes) { char* r = p + off; off += (bytes + 255) & ~(size_t)255; return r; };
  u16* ht_bf   = (u16*)alloc((size_t)NT * 128 * 2);
  u16* hs_bf   = (u16*)alloc((size_t)NT * 128 * 2);
  u16* hd_bf   = (u16*)alloc((size_t)NT * 128 * 2);
  u16* hc_bf   = (u16*)alloc((size_t)NC * 128 * 2);
  u16* x_bf    = (u16*)alloc((size_t)NT * 128 * 2);
  float* aS_sd = (float*)alloc((size_t)NT * 4 * 4);
  float* aD_sd = (float*)alloc((size_t)NT * 4 * 4);
  float* aS_ds = (float*)alloc((size_t)NT * 4 * 4);
  float* aD_ds = (float*)alloc((size_t)NT * 4 * 4);
  float* aS_ct = (float*)alloc((size_t)NC * 4 * 4);
  float* aD_ct = (float*)alloc((size_t)NT * 4 * 4);
  int* cntblk  = (int*)alloc((size_t)TOTC * 4);
  int* scanned = (int*)alloc((size_t)TOTC * 4);
  u32* bin     = (u32*)alloc((size_t)(2 * ETT + ECT) * 4);
  int* big_el  = (int*)alloc((size_t)(2 * ETT + ECT) * 4);
  int* offs    = (int*)alloc((size_t)3 * OFFS * 4);
  int* bsum    = (int*)alloc((size_t)NSB * 4);
  int* bpre    = (int*)alloc((size_t)NSB * 4);
  float* fold_cd = (float*)alloc(512 * 4);
  float* cbias   = (float*)alloc(128 * 4);
  u16* bfrag_sd  = (u16*)alloc((size_t)9 * 4 * 64 * 8 * 2);
  u16* bfrag_ds  = (u16*)alloc((size_t)9 * 4 * 64 * 8 * 2);
  u16* bfrag_out = (u16*)alloc((size_t)8 * 4 * 64 * 8 * 2);

  int* off_f = offs;
  int* off_r = offs + OFFS;
  int* off_c = offs + 2 * OFFS;
  int* el_f = big_el;
  int* el_r = big_el + ETT;
  int* el_c = big_el + 2 * ETT;

  const int* tt_src = e_tt;
  const int* tt_dst = e_tt + ETT;

  const int gT = (NT + 31) / 32;       // 3125
  const int gC = (NC + 31) / 32;       // 782
  const int gM = (NT + 63) / 64;       // 1563 (MFMA blocks)

  // CSR build (bucket-binned counting sort, no global atomics)
  hist_blk_kernel<<<NBLK, 256, 0, stream>>>(tt_src, tt_dst, ect_d, cntblk);
  scan2_blk_kernel<<<NSB, 256, 0, stream>>>(cntblk, scanned, bsum);
  scan2_top_kernel<<<1, 512, 0, stream>>>(bsum, bpre);
  scan2_add_kernel<<<NSB, 256, 0, stream>>>(bpre, scanned);
  bin_kernel<<<NBLK, 256, 0, stream>>>(tt_src, tt_dst, ect_s, ect_d, scanned, bin);
  bucket_fill_kernel<<<3 * NBK, 256, 0, stream>>>(scanned, bin, offs, big_el);

  // weight prep: MFMA frag layouts + fold_cd + cbias (4 blocks)
  prep_kernel<<<4, 256, 0, stream>>>(Wsd, As_sd, Ad_sd, Wds, As_ds, Ad_ds, Wout,
                                     bfrag_sd, bfrag_ds, bfrag_out,
                                     Wcd, Ad_ct, bsd, bds, bct, fold_cd, cbias);

  // node transforms
  pre_t_kernel<<<gT, 256, 0, stream>>>(x_t, Wpt, bpt, fold_cd, ht_bf, aD_ct, NT);
  mfma_logits2_kernel<<<gM, 256, 0, stream>>>((const short*)ht_bf,
      (const short*)bfrag_sd, (const short*)bfrag_ds,
      hs_bf, aS_sd, aD_sd, hd_bf, aS_ds, aD_ds, NT);
  ctx_kernel<<<gC, 256, 0, stream>>>(x_c, Wpc, bpc, Wcs, As_ct, hc_bf, aS_ct, NC);

  // fused gather (sd + ds + ct + cbias + skip + relu) -> x_bf
  gather_all_kernel<<<(NT + 15) / 16, 256, 0, stream>>>(
      off_f, el_f, aS_sd, aD_sd, hs_bf,
      off_r, el_r, aS_ds, aD_ds, hd_bf,
      off_c, el_c, aS_ct, aD_ct, hc_bf,
      ht_bf, cbias, x_bf);

  // final MFMA GEMM -> d_out (fp32)
  mfma_out_kernel<<<gM, 256, 0, stream>>>((const short*)x_bf, (const short*)bfrag_out,
                                          bout, (float*)d_out, NT);
}

// Round 4
// 428.394 us; speedup vs baseline: 1.0388x; 1.0140x over previous
//
#include <hip/hip_runtime.h>
#include <cstdint>
#include <cstddef>

typedef unsigned short u16;
typedef unsigned int u32;

#define NT 100000
#define NC 25000
#define ETT 800000
#define ECT 400000
#define SLOPE 0.2f
#define LOG2E 1.4426950408889634f
#define OFFS (NT + 4)           // padded stride for offset arrays (16B-aligned)

// bucket-binned CSR build
#define NBK 782                 // ceil(NT/128) buckets of 128 nodes
#define NBLK 256                // binning blocks
#define CHT ((ETT + NBLK - 1) / NBLK)   // 3125 tt edges / block
#define CHC ((ECT + NBLK - 1) / NBLK)   // 1563 ct edges / block
#define TOTC (3 * NBK * NBLK)           // 600576 counts
#define NSB ((TOTC + 2047) / 2048)      // 294 scan blocks

typedef __attribute__((ext_vector_type(8))) short bf16x8;
typedef __attribute__((ext_vector_type(4))) float f32x4;

__device__ __forceinline__ u16 f2bf(float f) {
  u32 u = __float_as_uint(f);
  u32 r = (u >> 16) & 1u;
  return (u16)((u + 0x7fffu + r) >> 16);
}
__device__ __forceinline__ float lof(u32 p) { return __uint_as_float(p << 16); }
__device__ __forceinline__ float hif(u32 p) { return __uint_as_float(p & 0xffff0000u); }

// ---------- merged transform kernel: prep (4 blocks) + pre_t (3125) + ctx (782) ----------
// prep blocks: MFMA B-frag layouts (+ attention-fold cols, LOG2E-prescaled) + cbias.
// pre_t blocks: h_t(bf16) = relu(x_t @ Wpt + b); aD_ct = relu(h_t) @ fold_cd.
//   fold_cd (512 dots of 32) is self-computed per block -- removes the prep->pre_t
//   dependency so all three paths can live in ONE kernel (block-range branch).
// ctx blocks: hcs = relu(x_c @ Wpc + b) @ Wcs (bf16) + a_s_ct logits.
#define GT_BLK ((NT + 31) / 32)   // 3125
#define GC_BLK ((NC + 31) / 32)   // 782

__global__ __launch_bounds__(256) void transform_kernel(
    const float* __restrict__ Wsd, const float* __restrict__ AsSd, const float* __restrict__ AdSd,
    const float* __restrict__ Wds, const float* __restrict__ AsDs, const float* __restrict__ AdDs,
    const float* __restrict__ Wout,
    u16* __restrict__ bf_sd, u16* __restrict__ bf_ds, u16* __restrict__ bf_out,
    const float* __restrict__ Wcd, const float* __restrict__ attD,
    const float* __restrict__ bsd, const float* __restrict__ bds, const float* __restrict__ bct,
    float* __restrict__ cbias,
    const float* __restrict__ x_t, const float* __restrict__ Wpt, const float* __restrict__ bpt,
    u16* __restrict__ h_t, float* __restrict__ aD,
    const float* __restrict__ x_c, const float* __restrict__ Wpc, const float* __restrict__ bpc,
    const float* __restrict__ Wcs, const float* __restrict__ attS,
    u16* __restrict__ hc_bf, float* __restrict__ aS_c)
{
  __shared__ float s_a[32][33];
  __shared__ float s_b[32][128];
  __shared__ float s_c[32][132];
  const int b = blockIdx.x;
  const int t = threadIdx.x;

  if (b < 4) {
    // ---------------- prep path ----------------
    if (b == 3) {
      if (t < 128) cbias[t] = 0.25f * bsd[t] + 0.25f * bds[t] + 0.5f * bct[t];
      return;
    }
    float* fS = &s_c[0][0];
    float* fD = fS + 512;
    const float* W = (b == 0) ? Wsd : (b == 1) ? Wds : Wout;
    const float* As = (b == 0) ? AsSd : AsDs;
    const float* Ad = (b == 0) ? AdSd : AdDs;
    u16* out = (b == 0) ? bf_sd : (b == 1) ? bf_ds : bf_out;
    const int tiles = (b == 2) ? 8 : 9;
    if (b < 2) {
      if (t < 128) {
        for (int h = 0; h < 4; ++h) {
          float s1 = 0.f, s2 = 0.f;
          for (int c = 0; c < 32; ++c) {
            const float wv = W[t * 128 + h * 32 + c];
            s1 = fmaf(wv, As[h * 32 + c], s1);
            s2 = fmaf(wv, Ad[h * 32 + c], s2);
          }
          fS[t * 4 + h] = s1 * LOG2E; fD[t * 4 + h] = s2 * LOG2E;
        }
      }
      __syncthreads();
    }
    const int total = tiles * 4 * 64 * 8;
    for (int i = t; i < total; i += 256) {
      const int j = i & 7, lane = (i >> 3) & 63, ks = (i >> 9) & 3, ti = i >> 11;
      const int k = ks * 32 + (lane >> 4) * 8 + j;
      const int n = ti * 16 + (lane & 15);
      float v;
      if (n < 128) v = W[k * 128 + n];
      else if (n < 132) v = fS[k * 4 + (n - 128)];
      else if (n < 136) v = fD[k * 4 + (n - 132)];
      else v = 0.f;
      out[i] = f2bf(v);
    }
    return;
  }

  if (b < 4 + GT_BLK) {
    // ---------------- pre_t path ----------------
    float* s_fold = &s_c[0][0];        // 512 floats
    if (t < 128) {
      for (int h = 0; h < 4; ++h) {
        float s = 0.f;
        for (int c = 0; c < 32; ++c)
          s = fmaf(Wcd[t * 128 + h * 32 + c], attD[h * 32 + c], s);
        s_fold[t * 4 + h] = s * LOG2E;
      }
    }
    const int row0 = (b - 4) * 32;
    const int rl = t >> 3, cg = t & 7;
    const int gr = row0 + rl;
    float acc[4][4];
    for (int g = 0; g < 4; ++g)
      for (int j = 0; j < 4; ++j)
        acc[g][j] = bpt[g * 32 + cg * 4 + j];
    for (int kc = 0; kc < 64; kc += 32) {
      {
        float4 f = make_float4(0.f, 0.f, 0.f, 0.f);
        if (gr < NT) f = *(const float4*)(x_t + (size_t)gr * 64 + kc + cg * 4);
        s_a[rl][cg * 4 + 0] = f.x; s_a[rl][cg * 4 + 1] = f.y;
        s_a[rl][cg * 4 + 2] = f.z; s_a[rl][cg * 4 + 3] = f.w;
      }
      for (int j = 0; j < 4; ++j) {
        const int idx = t + j * 256;
        const int k = idx >> 5, c4 = (idx & 31) * 4;
        *(float4*)&s_b[k][c4] = *(const float4*)(Wpt + (size_t)(kc + k) * 128 + c4);
      }
      __syncthreads();
#pragma unroll 8
      for (int k = 0; k < 32; ++k) {
        const float a = s_a[rl][k];
        for (int g = 0; g < 4; ++g) {
          const float4 w = *(const float4*)&s_b[k][g * 32 + cg * 4];
          acc[g][0] = fmaf(a, w.x, acc[g][0]);
          acc[g][1] = fmaf(a, w.y, acc[g][1]);
          acc[g][2] = fmaf(a, w.z, acc[g][2]);
          acc[g][3] = fmaf(a, w.w, acc[g][3]);
        }
      }
      __syncthreads();
    }
    if (gr < NT) {
      float p0 = 0.f, p1 = 0.f, p2 = 0.f, p3 = 0.f;
      for (int g = 0; g < 4; ++g) {
        for (int j = 0; j < 4; ++j) acc[g][j] = fmaxf(acc[g][j], 0.f);
        uint2 pk;
        pk.x = (u32)f2bf(acc[g][0]) | ((u32)f2bf(acc[g][1]) << 16);
        pk.y = (u32)f2bf(acc[g][2]) | ((u32)f2bf(acc[g][3]) << 16);
        *(uint2*)(h_t + (size_t)gr * 128 + g * 32 + cg * 4) = pk;
        for (int j = 0; j < 4; ++j) {
          const int col = g * 32 + cg * 4 + j;
          const float4 f4 = *(const float4*)&s_fold[col * 4];
          const float a = acc[g][j];
          p0 = fmaf(a, f4.x, p0); p1 = fmaf(a, f4.y, p1);
          p2 = fmaf(a, f4.z, p2); p3 = fmaf(a, f4.w, p3);
        }
      }
      for (int m = 1; m < 8; m <<= 1) {
        p0 += __shfl_xor(p0, m); p1 += __shfl_xor(p1, m);
        p2 += __shfl_xor(p2, m); p3 += __shfl_xor(p3, m);
      }
      if (cg == 0) *(float4*)(aD + (size_t)gr * 4) = make_float4(p0, p1, p2, p3);
    }
    return;
  }

  // ---------------- ctx path ----------------
  {
    const int row0 = (b - 4 - GT_BLK) * 32;
    const int rl = t >> 3, cg = t & 7;
    const int gr = row0 + rl;
    {
      float4 f = make_float4(0.f, 0.f, 0.f, 0.f);
      if (gr < NC) f = *(const float4*)(x_c + (size_t)gr * 32 + cg * 4);
      s_a[rl][cg * 4 + 0] = f.x; s_a[rl][cg * 4 + 1] = f.y;
      s_a[rl][cg * 4 + 2] = f.z; s_a[rl][cg * 4 + 3] = f.w;
    }
    for (int j = 0; j < 4; ++j) {
      const int idx = t + j * 256;
      const int k = idx >> 5, c4 = (idx & 31) * 4;
      *(float4*)&s_b[k][c4] = *(const float4*)(Wpc + (size_t)k * 128 + c4);
    }
    __syncthreads();
    float acc[4][4];
    for (int g = 0; g < 4; ++g)
      for (int j = 0; j < 4; ++j) acc[g][j] = bpc[g * 32 + cg * 4 + j];
#pragma unroll 8
    for (int k = 0; k < 32; ++k) {
      const float a = s_a[rl][k];
      for (int g = 0; g < 4; ++g) {
        const float4 w = *(const float4*)&s_b[k][g * 32 + cg * 4];
        acc[g][0] = fmaf(a, w.x, acc[g][0]);
        acc[g][1] = fmaf(a, w.y, acc[g][1]);
        acc[g][2] = fmaf(a, w.z, acc[g][2]);
        acc[g][3] = fmaf(a, w.w, acc[g][3]);
      }
    }
    for (int g = 0; g < 4; ++g)
      *(float4*)&s_c[rl][g * 32 + cg * 4] =
          make_float4(fmaxf(acc[g][0], 0.f), fmaxf(acc[g][1], 0.f),
                      fmaxf(acc[g][2], 0.f), fmaxf(acc[g][3], 0.f));
    __syncthreads();
    float acc2[4][4];
    for (int g = 0; g < 4; ++g)
      for (int j = 0; j < 4; ++j) acc2[g][j] = 0.f;
    for (int kc = 0; kc < 128; kc += 32) {
      for (int j = 0; j < 4; ++j) {
        const int idx = t + j * 256;
        const int k = idx >> 5, c4 = (idx & 31) * 4;
        *(float4*)&s_b[k][c4] = *(const float4*)(Wcs + (size_t)(kc + k) * 128 + c4);
      }
      __syncthreads();
#pragma unroll 8
      for (int k = 0; k < 32; ++k) {
        const float a = s_c[rl][kc + k];
        for (int g = 0; g < 4; ++g) {
          const float4 w = *(const float4*)&s_b[k][g * 32 + cg * 4];
          acc2[g][0] = fmaf(a, w.x, acc2[g][0]);
          acc2[g][1] = fmaf(a, w.y, acc2[g][1]);
          acc2[g][2] = fmaf(a, w.z, acc2[g][2]);
          acc2[g][3] = fmaf(a, w.w, acc2[g][3]);
        }
      }
      __syncthreads();
    }
    if (gr < NC) {
      float pS[4];
      for (int g = 0; g < 4; ++g) {
        uint2 pk;
        pk.x = (u32)f2bf(acc2[g][0]) | ((u32)f2bf(acc2[g][1]) << 16);
        pk.y = (u32)f2bf(acc2[g][2]) | ((u32)f2bf(acc2[g][3]) << 16);
        *(uint2*)(hc_bf + (size_t)gr * 128 + g * 32 + cg * 4) = pk;
        const float4 as4 = *(const float4*)(attS + g * 32 + cg * 4);
        pS[g] = acc2[g][0] * as4.x + acc2[g][1] * as4.y + acc2[g][2] * as4.z + acc2[g][3] * as4.w;
      }
      for (int m = 1; m < 8; m <<= 1)
        for (int g = 0; g < 4; ++g) pS[g] += __shfl_xor(pS[g], m);
      if (cg == 0)
        *(float4*)(aS_c + (size_t)gr * 4) =
            make_float4(pS[0] * LOG2E, pS[1] * LOG2E, pS[2] * LOG2E, pS[3] * LOG2E);
    }
  }
}

// ---------- fused MFMA GEMM x2 (sd + ds), N=144 each: bf16 out + aS/aD logits ----------
__global__ __launch_bounds__(256) void mfma_logits2_kernel(
    const short* __restrict__ A, const short* __restrict__ Bsd, const short* __restrict__ Bds,
    u16* __restrict__ hs, float* __restrict__ aSsd, float* __restrict__ aDsd,
    u16* __restrict__ hd, float* __restrict__ aSds, float* __restrict__ aDds, int M)
{
  __shared__ __align__(16) float lds[4][16][148];
  const int wv = threadIdx.x >> 6, lane = threadIdx.x & 63;
  const int quad = lane >> 4, l16 = lane & 15;
  const int row0 = blockIdx.x * 64 + wv * 16;
  const int arow = min(row0 + l16, M - 1);
  const short* ap = A + (size_t)arow * 128 + quad * 8;
  bf16x8 af[4];
  for (int ks = 0; ks < 4; ++ks) af[ks] = *(const bf16x8*)(ap + ks * 32);
  const int row = row0 + l16;
  const int idx = lane & 7, rr = lane >> 3;
  for (int pass = 0; pass < 2; ++pass) {
    const short* B = pass ? Bds : Bsd;
    u16* outb = pass ? hd : hs;
    float* aS = pass ? aSds : aSsd;
    float* aD = pass ? aDds : aDsd;
    f32x4 acc[9];
    for (int t = 0; t < 9; ++t) acc[t] = (f32x4){0.f, 0.f, 0.f, 0.f};
    for (int ks = 0; ks < 4; ++ks)
      for (int t = 0; t < 9; ++t) {
        const bf16x8 bf = *(const bf16x8*)(B + ((t * 4 + ks) * 64 + lane) * 8);
        acc[t] = __builtin_amdgcn_mfma_f32_16x16x32_bf16(af[ks], bf, acc[t], 0, 0, 0);
      }
    for (int t = 0; t < 9; ++t)
      for (int r = 0; r < 4; ++r)
        lds[wv][quad * 4 + r][t * 16 + l16] = acc[t][r];
    __syncthreads();
    if (row < M) {
      for (int g = 0; g < 8; ++g) {
        const f32x4 v = *(const f32x4*)&lds[wv][l16][g * 16 + quad * 4];
        uint2 pk;
        pk.x = (u32)f2bf(v[0]) | ((u32)f2bf(v[1]) << 16);
        pk.y = (u32)f2bf(v[2]) | ((u32)f2bf(v[3]) << 16);
        *(uint2*)(outb + (size_t)row * 128 + g * 16 + quad * 4) = pk;
      }
    }
    for (int p = 0; p < 2; ++p) {
      const int lr = p * 8 + rr;
      const int n = row0 + lr;
      if (n < M) {
        const float v = lds[wv][lr][128 + idx];
        if (idx < 4) aS[(size_t)n * 4 + idx] = v;
        else aD[(size_t)n * 4 + idx - 4] = v;
      }
    }
    __syncthreads();
  }
}

// ---------- MFMA GEMM, N=128 (8 tiles) + bias -> fp32 out ----------
__global__ __launch_bounds__(256) void mfma_out_kernel(
    const short* __restrict__ A, const short* __restrict__ B,
    const float* __restrict__ bias, float* __restrict__ out, int M)
{
  __shared__ __align__(16) float lds[4][16][132];
  const int wv = threadIdx.x >> 6, lane = threadIdx.x & 63;
  const int quad = lane >> 4, l16 = lane & 15;
  const int row0 = blockIdx.x * 64 + wv * 16;
  const int arow = min(row0 + l16, M - 1);
  const short* ap = A + (size_t)arow * 128 + quad * 8;
  bf16x8 af[4];
  for (int ks = 0; ks < 4; ++ks) af[ks] = *(const bf16x8*)(ap + ks * 32);
  f32x4 acc[8];
  for (int t = 0; t < 8; ++t) acc[t] = (f32x4){0.f, 0.f, 0.f, 0.f};
  for (int ks = 0; ks < 4; ++ks)
    for (int t = 0; t < 8; ++t) {
      const bf16x8 bf = *(const bf16x8*)(B + ((t * 4 + ks) * 64 + lane) * 8);
      acc[t] = __builtin_amdgcn_mfma_f32_16x16x32_bf16(af[ks], bf, acc[t], 0, 0, 0);
    }
  for (int t = 0; t < 8; ++t)
    for (int r = 0; r < 4; ++r)
      lds[wv][quad * 4 + r][t * 16 + l16] = acc[t][r];
  __syncthreads();
  const int row = row0 + l16;
  if (row < M) {
    for (int g = 0; g < 8; ++g) {
      const int col = g * 16 + quad * 4;
      f32x4 v = *(const f32x4*)&lds[wv][l16][col];
      const f32x4 b4 = *(const f32x4*)(bias + col);
      v = v + b4;
      *(f32x4*)(out + (size_t)row * 128 + col) = v;
    }
  }
}

// ---------- bucket-binned CSR build (no global atomics) ----------
__global__ __launch_bounds__(256) void hist_blk_kernel(const int* __restrict__ tt_src,
    const int* __restrict__ tt_dst, const int* __restrict__ ect_d, int* __restrict__ cntblk)
{
  __shared__ int h[3 * NBK];
  const int t = threadIdx.x, b = blockIdx.x;
  for (int i = t; i < 3 * NBK; i += 256) h[i] = 0;
  __syncthreads();
  const int lo = b * CHT, hi = min(lo + CHT, ETT);
  for (int i = lo + t; i < hi; i += 256) {
    atomicAdd(&h[tt_dst[i] >> 7], 1);
    atomicAdd(&h[NBK + (tt_src[i] >> 7)], 1);
  }
  const int lo2 = b * CHC, hi2 = min(lo2 + CHC, ECT);
  for (int i = lo2 + t; i < hi2; i += 256)
    atomicAdd(&h[2 * NBK + (ect_d[i] >> 7)], 1);
  __syncthreads();
  for (int i = t; i < 3 * NBK; i += 256)
    cntblk[(size_t)i * NBLK + b] = h[i];
}

// scan2_blk: per-2048-chunk exclusive scan (partial) + chunk totals.
// The top-level prefix (bpre) is ADDED BY CONSUMERS (bin/bucket_fill) --
// the former scan2_add kernel is eliminated.
__global__ __launch_bounds__(256) void scan2_blk_kernel(const int* __restrict__ in,
    int* __restrict__ out, int* __restrict__ bsum)
{
  const int t = threadIdx.x, b = blockIdx.x;
  const int idx = b * 2048 + t * 8;
  int v[8];
  int s = 0;
  if (idx < TOTC) {
    const int4 q0 = *(const int4*)(in + idx);
    const int4 q1 = *(const int4*)(in + idx + 4);
    int x;
    x = q0.x; v[0] = s; s += x;  x = q0.y; v[1] = s; s += x;
    x = q0.z; v[2] = s; s += x;  x = q0.w; v[3] = s; s += x;
    x = q1.x; v[4] = s; s += x;  x = q1.y; v[5] = s; s += x;
    x = q1.z; v[6] = s; s += x;  x = q1.w; v[7] = s; s += x;
  } else {
    for (int j = 0; j < 8; ++j) v[j] = 0;
  }
  __shared__ int sh[256];
  sh[t] = s;
  __syncthreads();
  for (int d = 1; d < 256; d <<= 1) {
    const int u = (t >= d) ? sh[t - d] : 0;
    __syncthreads();
    sh[t] += u;
    __syncthreads();
  }
  const int excl = (t == 0) ? 0 : sh[t - 1];
  if (idx < TOTC) {
    int4 q0, q1;
    q0.x = excl + v[0]; q0.y = excl + v[1]; q0.z = excl + v[2]; q0.w = excl + v[3];
    q1.x = excl + v[4]; q1.y = excl + v[5]; q1.z = excl + v[6]; q1.w = excl + v[7];
    *(int4*)(out + idx) = q0;
    *(int4*)(out + idx + 4) = q1;
  }
  if (t == 255) bsum[b] = sh[255];
}

__global__ __launch_bounds__(512) void scan2_top_kernel(const int* __restrict__ bsum,
    int* __restrict__ bpre)
{
  __shared__ int sh[512];
  const int t = threadIdx.x;
  const int orig = (t < NSB) ? bsum[t] : 0;
  sh[t] = orig;
  __syncthreads();
  for (int d = 1; d < 512; d <<= 1) {
    const int v = (t >= d) ? sh[t - d] : 0;
    __syncthreads();
    sh[t] += v;
    __syncthreads();
  }
  if (t < NSB) bpre[t] = sh[t] - orig;
}

__global__ __launch_bounds__(256) void bin_kernel(const int* __restrict__ tt_src,
    const int* __restrict__ tt_dst, const int* __restrict__ ect_s, const int* __restrict__ ect_d,
    const int* __restrict__ scanned, const int* __restrict__ bpre, u32* __restrict__ bin)
{
  __shared__ int cur[3 * NBK];
  const int t = threadIdx.x, b = blockIdx.x;
  for (int i = t; i < 3 * NBK; i += 256) {
    const int idx = i * NBLK + b;
    cur[i] = scanned[idx] + bpre[idx >> 11];
  }
  __syncthreads();
  const int lo = b * CHT, hi = min(lo + CHT, ETT);
  for (int i = lo + t; i < hi; i += 256) {
    const int s = tt_src[i], d = tt_dst[i];
    int p = atomicAdd(&cur[d >> 7], 1);
    bin[p] = ((u32)(d & 127) << 17) | (u32)s;
    p = atomicAdd(&cur[NBK + (s >> 7)], 1);
    bin[p] = ((u32)(s & 127) << 17) | (u32)d;
  }
  const int lo2 = b * CHC, hi2 = min(lo2 + CHC, ECT);
  for (int i = lo2 + t; i < hi2; i += 256) {
    const int s = ect_s[i], d = ect_d[i];
    const int p = atomicAdd(&cur[2 * NBK + (d >> 7)], 1);
    bin[p] = ((u32)(d & 127) << 17) | (u32)s;
  }
}

__global__ __launch_bounds__(256) void bucket_fill_kernel(const int* __restrict__ scanned,
    const int* __restrict__ bpre, const u32* __restrict__ bin,
    int* __restrict__ offs, int* __restrict__ big_el)
{
  const int rel = blockIdx.x / NBK;
  const int bucket = blockIdx.x - rel * NBK;
  const int t = threadIdx.x;
  __shared__ int s_cnt[128], s_exc[128], s_cur[128];
  if (t < 128) s_cnt[t] = 0;
  __syncthreads();
  const int bi = blockIdx.x * NBLK;
  const int base = scanned[bi] + bpre[bi >> 11];
  const int nxt = (blockIdx.x == 3 * NBK - 1) ? (2 * ETT + ECT)
                                              : scanned[bi + NBLK] + bpre[(bi + NBLK) >> 11];
  const int size = nxt - base;
  for (int i = t; i < size; i += 256)
    atomicAdd(&s_cnt[bin[base + i] >> 17], 1);
  __syncthreads();
  if (t < 128) s_exc[t] = s_cnt[t];
  __syncthreads();
  for (int d = 1; d < 128; d <<= 1) {
    int v = 0;
    if (t < 128 && t >= d) v = s_exc[t - d];
    __syncthreads();
    if (t < 128) s_exc[t] += v;
    __syncthreads();
  }
  const int relbase = rel * ETT;
  const int obase = base - relbase;
  int* off_rel = offs + (size_t)rel * OFFS;
  const int node0 = bucket * 128;
  if (t < 128) {
    const int excl = s_exc[t] - s_cnt[t];
    s_cur[t] = obase + excl;
    if (node0 + t < NT) off_rel[node0 + t] = obase + excl;
  }
  if (t == 0 && bucket == NBK - 1) off_rel[NT] = obase + size;
  __syncthreads();
  int* el_rel = big_el + relbase;
  for (int i = t; i < size; i += 256) {
    const u32 e = bin[base + i];
    const int pos = atomicAdd(&s_cur[e >> 17], 1);
    el_rel[pos] = (int)(e & 0x1FFFFu);
  }
}

// ---------- K5: fused 3-relation gather; 16-lane group per dst, 8 ch/lane ----------
// Round-0 depth-1 pipeline (fastest measured: 107.7us) with exp2f (logits are
// LOG2E-prescaled upstream). Gather is at its structural memory roofline
// (~3.5 TB/s L2-miss path on scattered 256B rows); deeper pipelining, higher
// occupancy and request reduction all measured null (R0/R2/R3).
__device__ __forceinline__ void gat_pipe16(const int* __restrict__ off,
    const int* __restrict__ el, const float* __restrict__ aS, const float* __restrict__ aD,
    const u16* __restrict__ hb, int d, int h, int cb, int self_loop, float w,
    float* __restrict__ acc)
{
  const float ad = aD[(size_t)d * 4 + h];
  const int beg = off[d];
  const int m = off[d + 1] - beg;     // real edges
  const int cnt = m + self_loop;
  if (cnt <= 0) return;
  float den = 0.f;
  float a0 = 0.f, a1 = 0.f, a2 = 0.f, a3 = 0.f, a4 = 0.f, a5 = 0.f, a6 = 0.f, a7 = 0.f;
  int sB = (1 < m) ? el[beg + 1] : d;
  {
    const int sA0 = (0 < m) ? el[beg] : d;
    float eA = aS[(size_t)sA0 * 4 + h];
    uint4 pA = *(const uint4*)(hb + (size_t)sA0 * 128 + cb);
    for (int k = 0; k < cnt; ++k) {
      const int sC = (k + 2 < m) ? el[beg + k + 2] : d;
      const float eB = aS[(size_t)sB * 4 + h];
      const uint4 pB = *(const uint4*)(hb + (size_t)sB * 128 + cb);
      float ea = eA + ad;
      ea = ea > 0.f ? ea : SLOPE * ea;
      const float ex = exp2f(ea);
      den += ex;
      a0 = fmaf(ex, lof(pA.x), a0); a1 = fmaf(ex, hif(pA.x), a1);
      a2 = fmaf(ex, lof(pA.y), a2); a3 = fmaf(ex, hif(pA.y), a3);
      a4 = fmaf(ex, lof(pA.z), a4); a5 = fmaf(ex, hif(pA.z), a5);
      a6 = fmaf(ex, lof(pA.w), a6); a7 = fmaf(ex, hif(pA.w), a7);
      eA = eB; pA = pB; sB = sC;
    }
  }
  const float s = w / den;            // den > 0 since cnt > 0
  acc[0] = fmaf(a0, s, acc[0]); acc[1] = fmaf(a1, s, acc[1]);
  acc[2] = fmaf(a2, s, acc[2]); acc[3] = fmaf(a3, s, acc[3]);
  acc[4] = fmaf(a4, s, acc[4]); acc[5] = fmaf(a5, s, acc[5]);
  acc[6] = fmaf(a6, s, acc[6]); acc[7] = fmaf(a7, s, acc[7]);
}

__global__ __launch_bounds__(256) void gather_all_kernel(
    const int* __restrict__ off_f, const int* __restrict__ el_f,
    const float* __restrict__ aS_sd, const float* __restrict__ aD_sd, const u16* __restrict__ hs,
    const int* __restrict__ off_r, const int* __restrict__ el_r,
    const float* __restrict__ aS_ds, const float* __restrict__ aD_ds, const u16* __restrict__ hd,
    const int* __restrict__ off_c, const int* __restrict__ el_c,
    const float* __restrict__ aS_ct, const float* __restrict__ aD_ct, const u16* __restrict__ hc,
    const u16* __restrict__ skip, const float* __restrict__ cbias, u16* __restrict__ x)
{
  const int d = blockIdx.x * 16 + (threadIdx.x >> 4);
  if (d >= NT) return;
  const int lg = threadIdx.x & 15;    // lane in group
  const int h = lg >> 2;              // head for this lane's channels
  const int cb = lg * 8;              // channel base (8 channels per lane)
  float acc[8];
  for (int i = 0; i < 8; ++i) acc[i] = 0.f;
  gat_pipe16(off_f, el_f, aS_sd, aD_sd, hs, d, h, cb, 1, 0.25f, acc);
  gat_pipe16(off_r, el_r, aS_ds, aD_ds, hd, d, h, cb, 1, 0.25f, acc);
  gat_pipe16(off_c, el_c, aS_ct, aD_ct, hc, d, h, cb, 0, 0.5f, acc);
  const uint4 sk = *(const uint4*)(skip + (size_t)d * 128 + cb);
  const float4 cb0 = *(const float4*)(cbias + cb);
  const float4 cb1 = *(const float4*)(cbias + cb + 4);
  const float o0 = fmaxf(acc[0] + cb0.x + lof(sk.x), 0.f);
  const float o1 = fmaxf(acc[1] + cb0.y + hif(sk.x), 0.f);
  const float o2 = fmaxf(acc[2] + cb0.z + lof(sk.y), 0.f);
  const float o3 = fmaxf(acc[3] + cb0.w + hif(sk.y), 0.f);
  const float o4 = fmaxf(acc[4] + cb1.x + lof(sk.z), 0.f);
  const float o5 = fmaxf(acc[5] + cb1.y + hif(sk.z), 0.f);
  const float o6 = fmaxf(acc[6] + cb1.z + lof(sk.w), 0.f);
  const float o7 = fmaxf(acc[7] + cb1.w + hif(sk.w), 0.f);
  uint4 r;
  r.x = (u32)f2bf(o0) | ((u32)f2bf(o1) << 16);
  r.y = (u32)f2bf(o2) | ((u32)f2bf(o3) << 16);
  r.z = (u32)f2bf(o4) | ((u32)f2bf(o5) << 16);
  r.w = (u32)f2bf(o6) | ((u32)f2bf(o7) << 16);
  *(uint4*)(x + (size_t)d * 128 + cb) = r;
}

extern "C" void kernel_launch(void* const* d_in, const int* in_sizes, int n_in,
                              void* d_out, int out_size, void* d_ws, size_t ws_size,
                              hipStream_t stream)
{
  const float* x_t   = (const float*)d_in[0];
  const float* x_c   = (const float*)d_in[1];
  const int*   e_tt  = (const int*)d_in[2];
  const int*   ect_s = (const int*)d_in[3];
  const int*   ect_d = (const int*)d_in[4];
  const float* Wpt = (const float*)d_in[5];   const float* bpt = (const float*)d_in[6];
  const float* Wpc = (const float*)d_in[7];   const float* bpc = (const float*)d_in[8];
  const float* Wsd = (const float*)d_in[9];   const float* As_sd = (const float*)d_in[10];
  const float* Ad_sd = (const float*)d_in[11]; const float* bsd = (const float*)d_in[12];
  const float* Wds = (const float*)d_in[13];  const float* As_ds = (const float*)d_in[14];
  const float* Ad_ds = (const float*)d_in[15]; const float* bds = (const float*)d_in[16];
  const float* Wcs = (const float*)d_in[17];  const float* Wcd = (const float*)d_in[18];
  const float* As_ct = (const float*)d_in[19]; const float* Ad_ct = (const float*)d_in[20];
  const float* bct = (const float*)d_in[21];
  const float* Wout = (const float*)d_in[22]; const float* bout = (const float*)d_in[23];

  // workspace (~140 MB)
  char* p = (char*)d_ws;
  size_t off = 0;
  auto alloc = [&](size_t bytes) { char* r = p + off; off += (bytes + 255) & ~(size_t)255; return r; };
  u16* ht_bf   = (u16*)alloc((size_t)NT * 128 * 2);
  u16* hs_bf   = (u16*)alloc((size_t)NT * 128 * 2);
  u16* hd_bf   = (u16*)alloc((size_t)NT * 128 * 2);
  u16* hc_bf   = (u16*)alloc((size_t)NC * 128 * 2);
  u16* x_bf    = (u16*)alloc((size_t)NT * 128 * 2);
  float* aS_sd = (float*)alloc((size_t)NT * 4 * 4);
  float* aD_sd = (float*)alloc((size_t)NT * 4 * 4);
  float* aS_ds = (float*)alloc((size_t)NT * 4 * 4);
  float* aD_ds = (float*)alloc((size_t)NT * 4 * 4);
  float* aS_ct = (float*)alloc((size_t)NC * 4 * 4);
  float* aD_ct = (float*)alloc((size_t)NT * 4 * 4);
  int* cntblk  = (int*)alloc((size_t)TOTC * 4);
  int* scanned = (int*)alloc((size_t)TOTC * 4);
  u32* bin     = (u32*)alloc((size_t)(2 * ETT + ECT) * 4);
  int* big_el  = (int*)alloc((size_t)(2 * ETT + ECT) * 4);
  int* offs    = (int*)alloc((size_t)3 * OFFS * 4);
  int* bsum    = (int*)alloc((size_t)NSB * 4);
  int* bpre    = (int*)alloc((size_t)NSB * 4);
  float* cbias   = (float*)alloc(128 * 4);
  u16* bfrag_sd  = (u16*)alloc((size_t)9 * 4 * 64 * 8 * 2);
  u16* bfrag_ds  = (u16*)alloc((size_t)9 * 4 * 64 * 8 * 2);
  u16* bfrag_out = (u16*)alloc((size_t)8 * 4 * 64 * 8 * 2);

  int* off_f = offs;
  int* off_r = offs + OFFS;
  int* off_c = offs + 2 * OFFS;
  int* el_f = big_el;
  int* el_r = big_el + ETT;
  int* el_c = big_el + 2 * ETT;

  const int* tt_src = e_tt;
  const int* tt_dst = e_tt + ETT;

  const int gM = (NT + 63) / 64;       // 1563 (MFMA blocks)

  // CSR build (bucket-binned counting sort; bpre folded into consumers)
  hist_blk_kernel<<<NBLK, 256, 0, stream>>>(tt_src, tt_dst, ect_d, cntblk);
  scan2_blk_kernel<<<NSB, 256, 0, stream>>>(cntblk, scanned, bsum);
  scan2_top_kernel<<<1, 512, 0, stream>>>(bsum, bpre);
  bin_kernel<<<NBLK, 256, 0, stream>>>(tt_src, tt_dst, ect_s, ect_d, scanned, bpre, bin);
  bucket_fill_kernel<<<3 * NBK, 256, 0, stream>>>(scanned, bpre, bin, offs, big_el);

  // merged node transforms: prep (4 blocks) + pre_t (3125) + ctx (782)
  transform_kernel<<<4 + GT_BLK + GC_BLK, 256, 0, stream>>>(
      Wsd, As_sd, Ad_sd, Wds, As_ds, Ad_ds, Wout,
      bfrag_sd, bfrag_ds, bfrag_out,
      Wcd, Ad_ct, bsd, bds, bct, cbias,
      x_t, Wpt, bpt, ht_bf, aD_ct,
      x_c, Wpc, bpc, Wcs, As_ct, hc_bf, aS_ct);

  // sd/ds MFMA GEMMs + logits
  mfma_logits2_kernel<<<gM, 256, 0, stream>>>((const short*)ht_bf,
      (const short*)bfrag_sd, (const short*)bfrag_ds,
      hs_bf, aS_sd, aD_sd, hd_bf, aS_ds, aD_ds, NT);

  // fused gather (sd + ds + ct + cbias + skip + relu) -> x_bf
  gather_all_kernel<<<(NT + 15) / 16, 256, 0, stream>>>(
      off_f, el_f, aS_sd, aD_sd, hs_bf,
      off_r, el_r, aS_ds, aD_ds, hd_bf,
      off_c, el_c, aS_ct, aD_ct, hc_bf,
      ht_bf, cbias, x_bf);

  // final MFMA GEMM -> d_out (fp32)
  mfma_out_kernel<<<gM, 256, 0, stream>>>((const short*)x_bf, (const short*)bfrag_out,
                                          bout, (float*)d_out, NT);
}

// Round 5
// 411.729 us; speedup vs baseline: 1.0808x; 1.0405x over previous
//
#include <hip/hip_runtime.h>
#include <cstdint>
#include <cstddef>

typedef unsigned short u16;
typedef unsigned int u32;

#define NT 100000
#define NC 25000
#define ETT 800000
#define ECT 400000
#define SLOPE 0.2f
#define LOG2E 1.4426950408889634f
#define OFFS (NT + 4)           // padded stride for offset arrays (16B-aligned)

// bucket-binned CSR build
#define NBK 782                 // ceil(NT/128) buckets of 128 nodes
#define NBLK 256                // binning blocks
#define CHT ((ETT + NBLK - 1) / NBLK)   // 3125 tt edges / block
#define CHC ((ECT + NBLK - 1) / NBLK)   // 1563 ct edges / block
#define TOTC (3 * NBK * NBLK)           // 600576 counts
#define NSB ((TOTC + 4095) / 4096)      // 147 scan blocks (<=256 so bpre fits one block-scan)
#define FILL_CAP 4096                   // LDS staging capacity for bucket_fill (ints)

#define GT_BLK ((NT + 31) / 32)   // 3125
#define GC_BLK ((NC + 31) / 32)   // 782

typedef __attribute__((ext_vector_type(8))) short bf16x8;
typedef __attribute__((ext_vector_type(4))) float f32x4;

__device__ __forceinline__ u16 f2bf(float f) {
  u32 u = __float_as_uint(f);
  u32 r = (u >> 16) & 1u;
  return (u16)((u + 0x7fffu + r) >> 16);
}
__device__ __forceinline__ float lof(u32 p) { return __uint_as_float(p << 16); }
__device__ __forceinline__ float hif(u32 p) { return __uint_as_float(p & 0xffff0000u); }

// exclusive prefix of bsum[0..NSB) into s_bpre[0..256). Replaces the former
// scan2_top kernel: each consumer block recomputes it in-LDS (sub-us).
__device__ __forceinline__ void compute_bpre(const int* __restrict__ bsum, int* s_bpre) {
  const int t = threadIdx.x;
  const int v = (t < NSB) ? bsum[t] : 0;
  s_bpre[t] = v;
  __syncthreads();
  for (int d = 1; d < 256; d <<= 1) {
    const int u = (t >= d) ? s_bpre[t - d] : 0;
    __syncthreads();
    s_bpre[t] += u;
    __syncthreads();
  }
  const int incl = s_bpre[t];
  __syncthreads();
  s_bpre[t] = incl - v;
  __syncthreads();
}

// ---------- K_A: hist (256 blocks) ∪ prep (4) ∪ pre_t (3125) ∪ ctx (782) ----------
// hist is independent of the transform paths; merging overlaps the CSR branch
// with the compute branch in one dispatch (no cross-path data deps).
__global__ __launch_bounds__(256) void transform_hist_kernel(
    const int* __restrict__ tt_src, const int* __restrict__ tt_dst,
    const int* __restrict__ ect_d, int* __restrict__ cntblk,
    const float* __restrict__ Wsd, const float* __restrict__ AsSd, const float* __restrict__ AdSd,
    const float* __restrict__ Wds, const float* __restrict__ AsDs, const float* __restrict__ AdDs,
    const float* __restrict__ Wout,
    u16* __restrict__ bf_sd, u16* __restrict__ bf_ds, u16* __restrict__ bf_out,
    const float* __restrict__ Wcd, const float* __restrict__ attD,
    const float* __restrict__ bsd, const float* __restrict__ bds, const float* __restrict__ bct,
    float* __restrict__ cbias,
    const float* __restrict__ x_t, const float* __restrict__ Wpt, const float* __restrict__ bpt,
    u16* __restrict__ h_t, float* __restrict__ aD,
    const float* __restrict__ x_c, const float* __restrict__ Wpc, const float* __restrict__ bpc,
    const float* __restrict__ Wcs, const float* __restrict__ attS,
    u16* __restrict__ hc_bf, float* __restrict__ aS_c)
{
  __shared__ float s_a[32][33];
  __shared__ float s_b[32][128];
  __shared__ float s_c[32][132];
  const int t = threadIdx.x;

  if (blockIdx.x < NBLK) {
    // ---------------- hist path ----------------
    int* h = (int*)&s_b[0][0];         // 4096 ints available, need 2346
    const int b = blockIdx.x;
    for (int i = t; i < 3 * NBK; i += 256) h[i] = 0;
    __syncthreads();
    const int lo = b * CHT, hi = min(lo + CHT, ETT);
    for (int i = lo + t; i < hi; i += 256) {
      atomicAdd(&h[tt_dst[i] >> 7], 1);
      atomicAdd(&h[NBK + (tt_src[i] >> 7)], 1);
    }
    const int lo2 = b * CHC, hi2 = min(lo2 + CHC, ECT);
    for (int i = lo2 + t; i < hi2; i += 256)
      atomicAdd(&h[2 * NBK + (ect_d[i] >> 7)], 1);
    __syncthreads();
    for (int i = t; i < 3 * NBK; i += 256)
      cntblk[(size_t)i * NBLK + b] = h[i];
    return;
  }

  const int b = blockIdx.x - NBLK;

  if (b < 4) {
    // ---------------- prep path ----------------
    if (b == 3) {
      if (t < 128) cbias[t] = 0.25f * bsd[t] + 0.25f * bds[t] + 0.5f * bct[t];
      return;
    }
    float* fS = &s_c[0][0];
    float* fD = fS + 512;
    const float* W = (b == 0) ? Wsd : (b == 1) ? Wds : Wout;
    const float* As = (b == 0) ? AsSd : AsDs;
    const float* Ad = (b == 0) ? AdSd : AdDs;
    u16* out = (b == 0) ? bf_sd : (b == 1) ? bf_ds : bf_out;
    const int tiles = (b == 2) ? 8 : 9;
    if (b < 2) {
      if (t < 128) {
        for (int h = 0; h < 4; ++h) {
          float s1 = 0.f, s2 = 0.f;
          for (int c = 0; c < 32; ++c) {
            const float wv = W[t * 128 + h * 32 + c];
            s1 = fmaf(wv, As[h * 32 + c], s1);
            s2 = fmaf(wv, Ad[h * 32 + c], s2);
          }
          fS[t * 4 + h] = s1 * LOG2E; fD[t * 4 + h] = s2 * LOG2E;
        }
      }
      __syncthreads();
    }
    const int total = tiles * 4 * 64 * 8;
    for (int i = t; i < total; i += 256) {
      const int j = i & 7, lane = (i >> 3) & 63, ks = (i >> 9) & 3, ti = i >> 11;
      const int k = ks * 32 + (lane >> 4) * 8 + j;
      const int n = ti * 16 + (lane & 15);
      float v;
      if (n < 128) v = W[k * 128 + n];
      else if (n < 132) v = fS[k * 4 + (n - 128)];
      else if (n < 136) v = fD[k * 4 + (n - 132)];
      else v = 0.f;
      out[i] = f2bf(v);
    }
    return;
  }

  if (b < 4 + GT_BLK) {
    // ---------------- pre_t path ----------------
    float* s_fold = &s_c[0][0];        // 512 floats
    if (t < 128) {
      for (int h = 0; h < 4; ++h) {
        float s = 0.f;
        for (int c = 0; c < 32; ++c)
          s = fmaf(Wcd[t * 128 + h * 32 + c], attD[h * 32 + c], s);
        s_fold[t * 4 + h] = s * LOG2E;
      }
    }
    const int row0 = (b - 4) * 32;
    const int rl = t >> 3, cg = t & 7;
    const int gr = row0 + rl;
    float acc[4][4];
    for (int g = 0; g < 4; ++g)
      for (int j = 0; j < 4; ++j)
        acc[g][j] = bpt[g * 32 + cg * 4 + j];
    for (int kc = 0; kc < 64; kc += 32) {
      {
        float4 f = make_float4(0.f, 0.f, 0.f, 0.f);
        if (gr < NT) f = *(const float4*)(x_t + (size_t)gr * 64 + kc + cg * 4);
        s_a[rl][cg * 4 + 0] = f.x; s_a[rl][cg * 4 + 1] = f.y;
        s_a[rl][cg * 4 + 2] = f.z; s_a[rl][cg * 4 + 3] = f.w;
      }
      for (int j = 0; j < 4; ++j) {
        const int idx = t + j * 256;
        const int k = idx >> 5, c4 = (idx & 31) * 4;
        *(float4*)&s_b[k][c4] = *(const float4*)(Wpt + (size_t)(kc + k) * 128 + c4);
      }
      __syncthreads();
#pragma unroll 8
      for (int k = 0; k < 32; ++k) {
        const float a = s_a[rl][k];
        for (int g = 0; g < 4; ++g) {
          const float4 w = *(const float4*)&s_b[k][g * 32 + cg * 4];
          acc[g][0] = fmaf(a, w.x, acc[g][0]);
          acc[g][1] = fmaf(a, w.y, acc[g][1]);
          acc[g][2] = fmaf(a, w.z, acc[g][2]);
          acc[g][3] = fmaf(a, w.w, acc[g][3]);
        }
      }
      __syncthreads();
    }
    if (gr < NT) {
      float p0 = 0.f, p1 = 0.f, p2 = 0.f, p3 = 0.f;
      for (int g = 0; g < 4; ++g) {
        for (int j = 0; j < 4; ++j) acc[g][j] = fmaxf(acc[g][j], 0.f);
        uint2 pk;
        pk.x = (u32)f2bf(acc[g][0]) | ((u32)f2bf(acc[g][1]) << 16);
        pk.y = (u32)f2bf(acc[g][2]) | ((u32)f2bf(acc[g][3]) << 16);
        *(uint2*)(h_t + (size_t)gr * 128 + g * 32 + cg * 4) = pk;
        for (int j = 0; j < 4; ++j) {
          const int col = g * 32 + cg * 4 + j;
          const float4 f4 = *(const float4*)&s_fold[col * 4];
          const float a = acc[g][j];
          p0 = fmaf(a, f4.x, p0); p1 = fmaf(a, f4.y, p1);
          p2 = fmaf(a, f4.z, p2); p3 = fmaf(a, f4.w, p3);
        }
      }
      for (int m = 1; m < 8; m <<= 1) {
        p0 += __shfl_xor(p0, m); p1 += __shfl_xor(p1, m);
        p2 += __shfl_xor(p2, m); p3 += __shfl_xor(p3, m);
      }
      if (cg == 0) *(float4*)(aD + (size_t)gr * 4) = make_float4(p0, p1, p2, p3);
    }
    return;
  }

  // ---------------- ctx path ----------------
  {
    const int row0 = (b - 4 - GT_BLK) * 32;
    const int rl = t >> 3, cg = t & 7;
    const int gr = row0 + rl;
    {
      float4 f = make_float4(0.f, 0.f, 0.f, 0.f);
      if (gr < NC) f = *(const float4*)(x_c + (size_t)gr * 32 + cg * 4);
      s_a[rl][cg * 4 + 0] = f.x; s_a[rl][cg * 4 + 1] = f.y;
      s_a[rl][cg * 4 + 2] = f.z; s_a[rl][cg * 4 + 3] = f.w;
    }
    for (int j = 0; j < 4; ++j) {
      const int idx = t + j * 256;
      const int k = idx >> 5, c4 = (idx & 31) * 4;
      *(float4*)&s_b[k][c4] = *(const float4*)(Wpc + (size_t)k * 128 + c4);
    }
    __syncthreads();
    float acc[4][4];
    for (int g = 0; g < 4; ++g)
      for (int j = 0; j < 4; ++j) acc[g][j] = bpc[g * 32 + cg * 4 + j];
#pragma unroll 8
    for (int k = 0; k < 32; ++k) {
      const float a = s_a[rl][k];
      for (int g = 0; g < 4; ++g) {
        const float4 w = *(const float4*)&s_b[k][g * 32 + cg * 4];
        acc[g][0] = fmaf(a, w.x, acc[g][0]);
        acc[g][1] = fmaf(a, w.y, acc[g][1]);
        acc[g][2] = fmaf(a, w.z, acc[g][2]);
        acc[g][3] = fmaf(a, w.w, acc[g][3]);
      }
    }
    for (int g = 0; g < 4; ++g)
      *(float4*)&s_c[rl][g * 32 + cg * 4] =
          make_float4(fmaxf(acc[g][0], 0.f), fmaxf(acc[g][1], 0.f),
                      fmaxf(acc[g][2], 0.f), fmaxf(acc[g][3], 0.f));
    __syncthreads();
    float acc2[4][4];
    for (int g = 0; g < 4; ++g)
      for (int j = 0; j < 4; ++j) acc2[g][j] = 0.f;
    for (int kc = 0; kc < 128; kc += 32) {
      for (int j = 0; j < 4; ++j) {
        const int idx = t + j * 256;
        const int k = idx >> 5, c4 = (idx & 31) * 4;
        *(float4*)&s_b[k][c4] = *(const float4*)(Wcs + (size_t)(kc + k) * 128 + c4);
      }
      __syncthreads();
#pragma unroll 8
      for (int k = 0; k < 32; ++k) {
        const float a = s_c[rl][kc + k];
        for (int g = 0; g < 4; ++g) {
          const float4 w = *(const float4*)&s_b[k][g * 32 + cg * 4];
          acc2[g][0] = fmaf(a, w.x, acc2[g][0]);
          acc2[g][1] = fmaf(a, w.y, acc2[g][1]);
          acc2[g][2] = fmaf(a, w.z, acc2[g][2]);
          acc2[g][3] = fmaf(a, w.w, acc2[g][3]);
        }
      }
      __syncthreads();
    }
    if (gr < NC) {
      float pS[4];
      for (int g = 0; g < 4; ++g) {
        uint2 pk;
        pk.x = (u32)f2bf(acc2[g][0]) | ((u32)f2bf(acc2[g][1]) << 16);
        pk.y = (u32)f2bf(acc2[g][2]) | ((u32)f2bf(acc2[g][3]) << 16);
        *(uint2*)(hc_bf + (size_t)gr * 128 + g * 32 + cg * 4) = pk;
        const float4 as4 = *(const float4*)(attS + g * 32 + cg * 4);
        pS[g] = acc2[g][0] * as4.x + acc2[g][1] * as4.y + acc2[g][2] * as4.z + acc2[g][3] * as4.w;
      }
      for (int m = 1; m < 8; m <<= 1)
        for (int g = 0; g < 4; ++g) pS[g] += __shfl_xor(pS[g], m);
      if (cg == 0)
        *(float4*)(aS_c + (size_t)gr * 4) =
            make_float4(pS[0] * LOG2E, pS[1] * LOG2E, pS[2] * LOG2E, pS[3] * LOG2E);
    }
  }
}

// ---------- scan2_blk: 4096-chunk exclusive scan (partial) + chunk totals ----------
__global__ __launch_bounds__(256) void scan2_blk_kernel(const int* __restrict__ in,
    int* __restrict__ out, int* __restrict__ bsum)
{
  const int t = threadIdx.x, b = blockIdx.x;
  const int idx = b * 4096 + t * 16;
  int v[16];
  int s = 0;
  if (idx < TOTC) {                     // TOTC % 16 == 0, so full 16 are safe
#pragma unroll
    for (int q = 0; q < 4; ++q) {
      const int4 qq = *(const int4*)(in + idx + q * 4);
      v[q * 4 + 0] = s; s += qq.x;
      v[q * 4 + 1] = s; s += qq.y;
      v[q * 4 + 2] = s; s += qq.z;
      v[q * 4 + 3] = s; s += qq.w;
    }
  } else {
    for (int j = 0; j < 16; ++j) v[j] = 0;
  }
  __shared__ int sh[256];
  sh[t] = s;
  __syncthreads();
  for (int d = 1; d < 256; d <<= 1) {
    const int u = (t >= d) ? sh[t - d] : 0;
    __syncthreads();
    sh[t] += u;
    __syncthreads();
  }
  const int excl = (t == 0) ? 0 : sh[t - 1];
  if (idx < TOTC) {
#pragma unroll
    for (int q = 0; q < 4; ++q) {
      int4 qo;
      qo.x = excl + v[q * 4 + 0]; qo.y = excl + v[q * 4 + 1];
      qo.z = excl + v[q * 4 + 2]; qo.w = excl + v[q * 4 + 3];
      *(int4*)(out + idx + q * 4) = qo;
    }
  }
  if (t == 255) bsum[b] = sh[255];
}

// ---------- K_C: bin (256 blocks) ∪ mfma_logits2 (1563 blocks) ----------
// bin depends only on scan; logits2 depends only on transform -- both satisfied,
// so they share one dispatch and overlap.
__global__ __launch_bounds__(256) void bin_logits2_kernel(
    const int* __restrict__ tt_src, const int* __restrict__ tt_dst,
    const int* __restrict__ ect_s, const int* __restrict__ ect_d,
    const int* __restrict__ scanned, const int* __restrict__ bsum, u32* __restrict__ bin,
    const short* __restrict__ A, const short* __restrict__ Bsd, const short* __restrict__ Bds,
    u16* __restrict__ hs, float* __restrict__ aSsd, float* __restrict__ aDsd,
    u16* __restrict__ hd, float* __restrict__ aSds, float* __restrict__ aDds, int M)
{
  __shared__ __align__(16) float ldsf[4][16][148];
  const int t = threadIdx.x;

  if (blockIdx.x < NBLK) {
    // ---------------- bin path ----------------
    int* cur = (int*)&ldsf[0][0][0];        // 2346 ints
    int* s_bpre = cur + 3 * NBK;            // 256 ints (total 10.4 KB < 37.9 KB)
    compute_bpre(bsum, s_bpre);
    const int b = blockIdx.x;
    for (int i = t; i < 3 * NBK; i += 256) {
      const int idx = i * NBLK + b;
      cur[i] = scanned[idx] + s_bpre[idx >> 12];
    }
    __syncthreads();
    const int lo = b * CHT, hi = min(lo + CHT, ETT);
    for (int i = lo + t; i < hi; i += 256) {
      const int s = tt_src[i], d = tt_dst[i];
      int p = atomicAdd(&cur[d >> 7], 1);
      bin[p] = ((u32)(d & 127) << 17) | (u32)s;
      p = atomicAdd(&cur[NBK + (s >> 7)], 1);
      bin[p] = ((u32)(s & 127) << 17) | (u32)d;
    }
    const int lo2 = b * CHC, hi2 = min(lo2 + CHC, ECT);
    for (int i = lo2 + t; i < hi2; i += 256) {
      const int s = ect_s[i], d = ect_d[i];
      const int p = atomicAdd(&cur[2 * NBK + (d >> 7)], 1);
      bin[p] = ((u32)(d & 127) << 17) | (u32)s;
    }
    return;
  }

  // ---------------- logits2 path ----------------
  float (*lds)[16][148] = ldsf;
  const int blk = blockIdx.x - NBLK;
  const int wv = t >> 6, lane = t & 63;
  const int quad = lane >> 4, l16 = lane & 15;
  const int row0 = blk * 64 + wv * 16;
  const int arow = min(row0 + l16, M - 1);
  const short* ap = A + (size_t)arow * 128 + quad * 8;
  bf16x8 af[4];
  for (int ks = 0; ks < 4; ++ks) af[ks] = *(const bf16x8*)(ap + ks * 32);
  const int row = row0 + l16;
  const int idx = lane & 7, rr = lane >> 3;
  for (int pass = 0; pass < 2; ++pass) {
    const short* B = pass ? Bds : Bsd;
    u16* outb = pass ? hd : hs;
    float* aS = pass ? aSds : aSsd;
    float* aD = pass ? aDds : aDsd;
    f32x4 acc[9];
    for (int ti = 0; ti < 9; ++ti) acc[ti] = (f32x4){0.f, 0.f, 0.f, 0.f};
    for (int ks = 0; ks < 4; ++ks)
      for (int ti = 0; ti < 9; ++ti) {
        const bf16x8 bf = *(const bf16x8*)(B + ((ti * 4 + ks) * 64 + lane) * 8);
        acc[ti] = __builtin_amdgcn_mfma_f32_16x16x32_bf16(af[ks], bf, acc[ti], 0, 0, 0);
      }
    for (int ti = 0; ti < 9; ++ti)
      for (int r = 0; r < 4; ++r)
        lds[wv][quad * 4 + r][ti * 16 + l16] = acc[ti][r];
    __syncthreads();
    if (row < M) {
      for (int g = 0; g < 8; ++g) {
        const f32x4 v = *(const f32x4*)&lds[wv][l16][g * 16 + quad * 4];
        uint2 pk;
        pk.x = (u32)f2bf(v[0]) | ((u32)f2bf(v[1]) << 16);
        pk.y = (u32)f2bf(v[2]) | ((u32)f2bf(v[3]) << 16);
        *(uint2*)(outb + (size_t)row * 128 + g * 16 + quad * 4) = pk;
      }
    }
    for (int p = 0; p < 2; ++p) {
      const int lr = p * 8 + rr;
      const int n = row0 + lr;
      if (n < M) {
        const float v = lds[wv][lr][128 + idx];
        if (idx < 4) aS[(size_t)n * 4 + idx] = v;
        else aD[(size_t)n * 4 + idx - 4] = v;
      }
    }
    __syncthreads();
  }
}

// ---------- bucket_fill: self-computed bpre + LDS-staged coalesced el output ----------
__global__ __launch_bounds__(256) void bucket_fill_kernel(const int* __restrict__ scanned,
    const int* __restrict__ bsum, const u32* __restrict__ bin,
    int* __restrict__ offs, int* __restrict__ big_el)
{
  __shared__ int s_cnt[128], s_exc[128], s_cur[128], s_bpre[256];
  __shared__ int s_el[FILL_CAP];
  const int t = threadIdx.x;
  compute_bpre(bsum, s_bpre);
  const int rel = blockIdx.x / NBK;
  const int bucket = blockIdx.x - rel * NBK;
  if (t < 128) s_cnt[t] = 0;
  const int bi = blockIdx.x * NBLK;
  const int base = scanned[bi] + s_bpre[bi >> 12];
  const int nxt = (blockIdx.x == 3 * NBK - 1)
                      ? (2 * ETT + ECT)
                      : scanned[bi + NBLK] + s_bpre[(bi + NBLK) >> 12];
  __syncthreads();
  const int size = nxt - base;
  for (int i = t; i < size; i += 256)
    atomicAdd(&s_cnt[bin[base + i] >> 17], 1);
  __syncthreads();
  if (t < 128) s_exc[t] = s_cnt[t];
  __syncthreads();
  for (int d = 1; d < 128; d <<= 1) {
    int v = 0;
    if (t < 128 && t >= d) v = s_exc[t - d];
    __syncthreads();
    if (t < 128) s_exc[t] += v;
    __syncthreads();
  }
  const int relbase = rel * ETT;
  const int obase = base - relbase;
  int* off_rel = offs + (size_t)rel * OFFS;
  const int node0 = bucket * 128;
  if (t < 128) {
    const int excl = s_exc[t] - s_cnt[t];
    s_cur[t] = excl;                    // bucket-LOCAL cursor
    if (node0 + t < NT) off_rel[node0 + t] = obase + excl;
  }
  if (t == 0 && bucket == NBK - 1) off_rel[NT] = obase + size;
  __syncthreads();
  int* el_rel = big_el + relbase;
  if (size <= FILL_CAP) {
    // scatter into LDS, then stream out coalesced (full lines)
    for (int i = t; i < size; i += 256) {
      const u32 e = bin[base + i];
      const int pos = atomicAdd(&s_cur[e >> 17], 1);
      s_el[pos] = (int)(e & 0x1FFFFu);
    }
    __syncthreads();
    for (int i = t; i < size; i += 256)
      el_rel[obase + i] = s_el[i];
  } else {
    // fallback (statistically unreachable: mean bucket size ~1k, cap 4k)
    for (int i = t; i < size; i += 256) {
      const u32 e = bin[base + i];
      const int pos = atomicAdd(&s_cur[e >> 17], 1);
      el_rel[obase + pos] = (int)(e & 0x1FFFFu);
    }
  }
}

// ---------- MFMA GEMM, N=128 (8 tiles) + bias -> fp32 out ----------
__global__ __launch_bounds__(256) void mfma_out_kernel(
    const short* __restrict__ A, const short* __restrict__ B,
    const float* __restrict__ bias, float* __restrict__ out, int M)
{
  __shared__ __align__(16) float lds[4][16][132];
  const int wv = threadIdx.x >> 6, lane = threadIdx.x & 63;
  const int quad = lane >> 4, l16 = lane & 15;
  const int row0 = blockIdx.x * 64 + wv * 16;
  const int arow = min(row0 + l16, M - 1);
  const short* ap = A + (size_t)arow * 128 + quad * 8;
  bf16x8 af[4];
  for (int ks = 0; ks < 4; ++ks) af[ks] = *(const bf16x8*)(ap + ks * 32);
  f32x4 acc[8];
  for (int t = 0; t < 8; ++t) acc[t] = (f32x4){0.f, 0.f, 0.f, 0.f};
  for (int ks = 0; ks < 4; ++ks)
    for (int t = 0; t < 8; ++t) {
      const bf16x8 bf = *(const bf16x8*)(B + ((t * 4 + ks) * 64 + lane) * 8);
      acc[t] = __builtin_amdgcn_mfma_f32_16x16x32_bf16(af[ks], bf, acc[t], 0, 0, 0);
    }
  for (int t = 0; t < 8; ++t)
    for (int r = 0; r < 4; ++r)
      lds[wv][quad * 4 + r][t * 16 + l16] = acc[t][r];
  __syncthreads();
  const int row = row0 + l16;
  if (row < M) {
    for (int g = 0; g < 8; ++g) {
      const int col = g * 16 + quad * 4;
      f32x4 v = *(const f32x4*)&lds[wv][l16][col];
      const f32x4 b4 = *(const f32x4*)(bias + col);
      v = v + b4;
      *(f32x4*)(out + (size_t)row * 128 + col) = v;
    }
  }
}

// ---------- K5: fused 3-relation gather; 16-lane group per dst, 8 ch/lane ----------
// Round-0 depth-1 pipeline (fastest measured) with exp2f (logits LOG2E-prescaled).
// Gather is at its structural memory roofline (~3.5 TB/s on scattered 256B rows);
// deeper pipelining, occupancy, and request reduction all measured null (R0/R2/R3).
__device__ __forceinline__ void gat_pipe16(const int* __restrict__ off,
    const int* __restrict__ el, const float* __restrict__ aS, const float* __restrict__ aD,
    const u16* __restrict__ hb, int d, int h, int cb, int self_loop, float w,
    float* __restrict__ acc)
{
  const float ad = aD[(size_t)d * 4 + h];
  const int beg = off[d];
  const int m = off[d + 1] - beg;     // real edges
  const int cnt = m + self_loop;
  if (cnt <= 0) return;
  float den = 0.f;
  float a0 = 0.f, a1 = 0.f, a2 = 0.f, a3 = 0.f, a4 = 0.f, a5 = 0.f, a6 = 0.f, a7 = 0.f;
  int sB = (1 < m) ? el[beg + 1] : d;
  {
    const int sA0 = (0 < m) ? el[beg] : d;
    float eA = aS[(size_t)sA0 * 4 + h];
    uint4 pA = *(const uint4*)(hb + (size_t)sA0 * 128 + cb);
    for (int k = 0; k < cnt; ++k) {
      const int sC = (k + 2 < m) ? el[beg + k + 2] : d;
      const float eB = aS[(size_t)sB * 4 + h];
      const uint4 pB = *(const uint4*)(hb + (size_t)sB * 128 + cb);
      float ea = eA + ad;
      ea = ea > 0.f ? ea : SLOPE * ea;
      const float ex = exp2f(ea);
      den += ex;
      a0 = fmaf(ex, lof(pA.x), a0); a1 = fmaf(ex, hif(pA.x), a1);
      a2 = fmaf(ex, lof(pA.y), a2); a3 = fmaf(ex, hif(pA.y), a3);
      a4 = fmaf(ex, lof(pA.z), a4); a5 = fmaf(ex, hif(pA.z), a5);
      a6 = fmaf(ex, lof(pA.w), a6); a7 = fmaf(ex, hif(pA.w), a7);
      eA = eB; pA = pB; sB = sC;
    }
  }
  const float s = w / den;            // den > 0 since cnt > 0
  acc[0] = fmaf(a0, s, acc[0]); acc[1] = fmaf(a1, s, acc[1]);
  acc[2] = fmaf(a2, s, acc[2]); acc[3] = fmaf(a3, s, acc[3]);
  acc[4] = fmaf(a4, s, acc[4]); acc[5] = fmaf(a5, s, acc[5]);
  acc[6] = fmaf(a6, s, acc[6]); acc[7] = fmaf(a7, s, acc[7]);
}

__global__ __launch_bounds__(256) void gather_all_kernel(
    const int* __restrict__ off_f, const int* __restrict__ el_f,
    const float* __restrict__ aS_sd, const float* __restrict__ aD_sd, const u16* __restrict__ hs,
    const int* __restrict__ off_r, const int* __restrict__ el_r,
    const float* __restrict__ aS_ds, const float* __restrict__ aD_ds, const u16* __restrict__ hd,
    const int* __restrict__ off_c, const int* __restrict__ el_c,
    const float* __restrict__ aS_ct, const float* __restrict__ aD_ct, const u16* __restrict__ hc,
    const u16* __restrict__ skip, const float* __restrict__ cbias, u16* __restrict__ x)
{
  const int d = blockIdx.x * 16 + (threadIdx.x >> 4);
  if (d >= NT) return;
  const int lg = threadIdx.x & 15;    // lane in group
  const int h = lg >> 2;              // head for this lane's channels
  const int cb = lg * 8;              // channel base (8 channels per lane)
  float acc[8];
  for (int i = 0; i < 8; ++i) acc[i] = 0.f;
  gat_pipe16(off_f, el_f, aS_sd, aD_sd, hs, d, h, cb, 1, 0.25f, acc);
  gat_pipe16(off_r, el_r, aS_ds, aD_ds, hd, d, h, cb, 1, 0.25f, acc);
  gat_pipe16(off_c, el_c, aS_ct, aD_ct, hc, d, h, cb, 0, 0.5f, acc);
  const uint4 sk = *(const uint4*)(skip + (size_t)d * 128 + cb);
  const float4 cb0 = *(const float4*)(cbias + cb);
  const float4 cb1 = *(const float4*)(cbias + cb + 4);
  const float o0 = fmaxf(acc[0] + cb0.x + lof(sk.x), 0.f);
  const float o1 = fmaxf(acc[1] + cb0.y + hif(sk.x), 0.f);
  const float o2 = fmaxf(acc[2] + cb0.z + lof(sk.y), 0.f);
  const float o3 = fmaxf(acc[3] + cb0.w + hif(sk.y), 0.f);
  const float o4 = fmaxf(acc[4] + cb1.x + lof(sk.z), 0.f);
  const float o5 = fmaxf(acc[5] + cb1.y + hif(sk.z), 0.f);
  const float o6 = fmaxf(acc[6] + cb1.z + lof(sk.w), 0.f);
  const float o7 = fmaxf(acc[7] + cb1.w + hif(sk.w), 0.f);
  uint4 r;
  r.x = (u32)f2bf(o0) | ((u32)f2bf(o1) << 16);
  r.y = (u32)f2bf(o2) | ((u32)f2bf(o3) << 16);
  r.z = (u32)f2bf(o4) | ((u32)f2bf(o5) << 16);
  r.w = (u32)f2bf(o6) | ((u32)f2bf(o7) << 16);
  *(uint4*)(x + (size_t)d * 128 + cb) = r;
}

extern "C" void kernel_launch(void* const* d_in, const int* in_sizes, int n_in,
                              void* d_out, int out_size, void* d_ws, size_t ws_size,
                              hipStream_t stream)
{
  const float* x_t   = (const float*)d_in[0];
  const float* x_c   = (const float*)d_in[1];
  const int*   e_tt  = (const int*)d_in[2];
  const int*   ect_s = (const int*)d_in[3];
  const int*   ect_d = (const int*)d_in[4];
  const float* Wpt = (const float*)d_in[5];   const float* bpt = (const float*)d_in[6];
  const float* Wpc = (const float*)d_in[7];   const float* bpc = (const float*)d_in[8];
  const float* Wsd = (const float*)d_in[9];   const float* As_sd = (const float*)d_in[10];
  const float* Ad_sd = (const float*)d_in[11]; const float* bsd = (const float*)d_in[12];
  const float* Wds = (const float*)d_in[13];  const float* As_ds = (const float*)d_in[14];
  const float* Ad_ds = (const float*)d_in[15]; const float* bds = (const float*)d_in[16];
  const float* Wcs = (const float*)d_in[17];  const float* Wcd = (const float*)d_in[18];
  const float* As_ct = (const float*)d_in[19]; const float* Ad_ct = (const float*)d_in[20];
  const float* bct = (const float*)d_in[21];
  const float* Wout = (const float*)d_in[22]; const float* bout = (const float*)d_in[23];

  // workspace (~140 MB)
  char* p = (char*)d_ws;
  size_t off = 0;
  auto alloc = [&](size_t bytes) { char* r = p + off; off += (bytes + 255) & ~(size_t)255; return r; };
  u16* ht_bf   = (u16*)alloc((size_t)NT * 128 * 2);
  u16* hs_bf   = (u16*)alloc((size_t)NT * 128 * 2);
  u16* hd_bf   = (u16*)alloc((size_t)NT * 128 * 2);
  u16* hc_bf   = (u16*)alloc((size_t)NC * 128 * 2);
  u16* x_bf    = (u16*)alloc((size_t)NT * 128 * 2);
  float* aS_sd = (float*)alloc((size_t)NT * 4 * 4);
  float* aD_sd = (float*)alloc((size_t)NT * 4 * 4);
  float* aS_ds = (float*)alloc((size_t)NT * 4 * 4);
  float* aD_ds = (float*)alloc((size_t)NT * 4 * 4);
  float* aS_ct = (float*)alloc((size_t)NC * 4 * 4);
  float* aD_ct = (float*)alloc((size_t)NT * 4 * 4);
  int* cntblk  = (int*)alloc((size_t)TOTC * 4);
  int* scanned = (int*)alloc((size_t)TOTC * 4);
  u32* bin     = (u32*)alloc((size_t)(2 * ETT + ECT) * 4);
  int* big_el  = (int*)alloc((size_t)(2 * ETT + ECT) * 4);
  int* offs    = (int*)alloc((size_t)3 * OFFS * 4);
  int* bsum    = (int*)alloc((size_t)NSB * 4);
  float* cbias   = (float*)alloc(128 * 4);
  u16* bfrag_sd  = (u16*)alloc((size_t)9 * 4 * 64 * 8 * 2);
  u16* bfrag_ds  = (u16*)alloc((size_t)9 * 4 * 64 * 8 * 2);
  u16* bfrag_out = (u16*)alloc((size_t)8 * 4 * 64 * 8 * 2);

  int* off_f = offs;
  int* off_r = offs + OFFS;
  int* off_c = offs + 2 * OFFS;
  int* el_f = big_el;
  int* el_r = big_el + ETT;
  int* el_c = big_el + 2 * ETT;

  const int* tt_src = e_tt;
  const int* tt_dst = e_tt + ETT;

  const int gM = (NT + 63) / 64;       // 1563 (MFMA blocks)

  // K_A: hist ∪ prep ∪ pre_t ∪ ctx (independent paths, one dispatch)
  transform_hist_kernel<<<NBLK + 4 + GT_BLK + GC_BLK, 256, 0, stream>>>(
      tt_src, tt_dst, ect_d, cntblk,
      Wsd, As_sd, Ad_sd, Wds, As_ds, Ad_ds, Wout,
      bfrag_sd, bfrag_ds, bfrag_out,
      Wcd, Ad_ct, bsd, bds, bct, cbias,
      x_t, Wpt, bpt, ht_bf, aD_ct,
      x_c, Wpc, bpc, Wcs, As_ct, hc_bf, aS_ct);

  // scan (147 blocks; top-level prefix recomputed by consumers in LDS)
  scan2_blk_kernel<<<NSB, 256, 0, stream>>>(cntblk, scanned, bsum);

  // K_C: bin ∪ sd/ds MFMA GEMMs+logits (independent, one dispatch)
  bin_logits2_kernel<<<NBLK + gM, 256, 0, stream>>>(
      tt_src, tt_dst, ect_s, ect_d, scanned, bsum, bin,
      (const short*)ht_bf, (const short*)bfrag_sd, (const short*)bfrag_ds,
      hs_bf, aS_sd, aD_sd, hd_bf, aS_ds, aD_ds, NT);

  // bucket_fill: CSR finalize (LDS-staged coalesced writes)
  bucket_fill_kernel<<<3 * NBK, 256, 0, stream>>>(scanned, bsum, bin, offs, big_el);

  // fused gather (sd + ds + ct + cbias + skip + relu) -> x_bf
  gather_all_kernel<<<(NT + 15) / 16, 256, 0, stream>>>(
      off_f, el_f, aS_sd, aD_sd, hs_bf,
      off_r, el_r, aS_ds, aD_ds, hd_bf,
      off_c, el_c, aS_ct, aD_ct, hc_bf,
      ht_bf, cbias, x_bf);

  // final MFMA GEMM -> d_out (fp32)
  mfma_out_kernel<<<gM, 256, 0, stream>>>((const short*)x_bf, (const short*)bfrag_out,
                                          bout, (float*)d_out, NT);
}

// Round 6
// 375.678 us; speedup vs baseline: 1.1845x; 1.0960x over previous
//
#include <hip/hip_runtime.h>
#include <cstdint>
#include <cstddef>

typedef unsigned short u16;
typedef unsigned int u32;

#define NT 100000
#define NC 25000
#define ETT 800000
#define ECT 400000
#define SLOPE 0.2f
#define LOG2E 1.4426950408889634f
#define OFFS (NT + 4)           // padded stride for offset arrays (16B-aligned)

// bucket-binned CSR build
#define NBK 782                 // ceil(NT/128) buckets of 128 nodes
#define NBLK 256                // binning blocks
#define CHT ((ETT + NBLK - 1) / NBLK)   // 3125 tt edges / block
#define CHC ((ECT + NBLK - 1) / NBLK)   // 1563 ct edges / block
#define TOTC (3 * NBK * NBLK)           // 600576 counts
#define NSB ((TOTC + 4095) / 4096)      // 147 scan blocks (<=256 so bpre fits one block-scan)
#define FILL_CAP 4096                   // LDS staging capacity for bucket_fill (ints)

#define PT_BLK ((NT + 63) / 64)   // 1563 pre_t blocks (64 rows each)
#define CT_BLK ((NC + 63) / 64)   // 391 ctx blocks

typedef __attribute__((ext_vector_type(8))) short bf16x8;
typedef __attribute__((ext_vector_type(4))) float f32x4;

__device__ __forceinline__ u16 f2bf(float f) {
  u32 u = __float_as_uint(f);
  u32 r = (u >> 16) & 1u;
  return (u16)((u + 0x7fffu + r) >> 16);
}
__device__ __forceinline__ float lof(u32 p) { return __uint_as_float(p << 16); }
__device__ __forceinline__ float hif(u32 p) { return __uint_as_float(p & 0xffff0000u); }

// exclusive prefix of bsum[0..NSB) into s_bpre[0..256). Replaces the former
// scan2_top kernel: each consumer block recomputes it in-LDS (sub-us).
__device__ __forceinline__ void compute_bpre(const int* __restrict__ bsum, int* s_bpre) {
  const int t = threadIdx.x;
  const int v = (t < NSB) ? bsum[t] : 0;
  s_bpre[t] = v;
  __syncthreads();
  for (int d = 1; d < 256; d <<= 1) {
    const int u = (t >= d) ? s_bpre[t - d] : 0;
    __syncthreads();
    s_bpre[t] += u;
    __syncthreads();
  }
  const int incl = s_bpre[t];
  __syncthreads();
  s_bpre[t] = incl - v;
  __syncthreads();
}

// ---------- K_A: hist (256) ∪ prep (4) ∪ pre_t (1563) ∪ ctx (391) ----------
// Transform paths are register-blocked (4 rows x 8 cols / thread) with the
// activation tile staged TRANSPOSED (s_xt[k][row]) so the inner loop is
// 3x ds_read_b128 per 32 FMA -> VALU-bound (was 30% VALUBusy, LDS-bound).
// fp32 FMA order over k is unchanged -> h_t/hc_bf bitwise identical.
__global__ __launch_bounds__(256) void transform_hist_kernel(
    const int* __restrict__ tt_src, const int* __restrict__ tt_dst,
    const int* __restrict__ ect_d, int* __restrict__ cntblk,
    const float* __restrict__ Wsd, const float* __restrict__ AsSd, const float* __restrict__ AdSd,
    const float* __restrict__ Wds, const float* __restrict__ AsDs, const float* __restrict__ AdDs,
    const float* __restrict__ Wout,
    u16* __restrict__ bf_sd, u16* __restrict__ bf_ds, u16* __restrict__ bf_out,
    const float* __restrict__ Wcd, const float* __restrict__ attD,
    const float* __restrict__ bsd, const float* __restrict__ bds, const float* __restrict__ bct,
    float* __restrict__ cbias,
    const float* __restrict__ x_t, const float* __restrict__ Wpt, const float* __restrict__ bpt,
    u16* __restrict__ h_t, float* __restrict__ aD,
    const float* __restrict__ x_c, const float* __restrict__ Wpc, const float* __restrict__ bpc,
    const float* __restrict__ Wcs, const float* __restrict__ attS,
    u16* __restrict__ hc_bf, float* __restrict__ aS_c)
{
  __shared__ __align__(16) char smem[51200];
  const int t = threadIdx.x;

  if (blockIdx.x < NBLK) {
    // ---------------- hist path ----------------
    int* h = (int*)smem;               // 2346 ints
    const int b = blockIdx.x;
    for (int i = t; i < 3 * NBK; i += 256) h[i] = 0;
    __syncthreads();
    const int lo = b * CHT, hi = min(lo + CHT, ETT);
    for (int i = lo + t; i < hi; i += 256) {
      atomicAdd(&h[tt_dst[i] >> 7], 1);
      atomicAdd(&h[NBK + (tt_src[i] >> 7)], 1);
    }
    const int lo2 = b * CHC, hi2 = min(lo2 + CHC, ECT);
    for (int i = lo2 + t; i < hi2; i += 256)
      atomicAdd(&h[2 * NBK + (ect_d[i] >> 7)], 1);
    __syncthreads();
    for (int i = t; i < 3 * NBK; i += 256)
      cntblk[(size_t)i * NBLK + b] = h[i];
    return;
  }

  const int b = blockIdx.x - NBLK;

  if (b < 4) {
    // ---------------- prep path ----------------
    if (b == 3) {
      if (t < 128) cbias[t] = 0.25f * bsd[t] + 0.25f * bds[t] + 0.5f * bct[t];
      return;
    }
    float* fS = (float*)smem;
    float* fD = fS + 512;
    const float* W = (b == 0) ? Wsd : (b == 1) ? Wds : Wout;
    const float* As = (b == 0) ? AsSd : AsDs;
    const float* Ad = (b == 0) ? AdSd : AdDs;
    u16* out = (b == 0) ? bf_sd : (b == 1) ? bf_ds : bf_out;
    const int tiles = (b == 2) ? 8 : 9;
    if (b < 2) {
      if (t < 128) {
        for (int hh = 0; hh < 4; ++hh) {
          float s1 = 0.f, s2 = 0.f;
          for (int c = 0; c < 32; ++c) {
            const float wv = W[t * 128 + hh * 32 + c];
            s1 = fmaf(wv, As[hh * 32 + c], s1);
            s2 = fmaf(wv, Ad[hh * 32 + c], s2);
          }
          fS[t * 4 + hh] = s1 * LOG2E; fD[t * 4 + hh] = s2 * LOG2E;
        }
      }
      __syncthreads();
    }
    const int total = tiles * 4 * 64 * 8;
    for (int i = t; i < total; i += 256) {
      const int j = i & 7, lane = (i >> 3) & 63, ks = (i >> 9) & 3, ti = i >> 11;
      const int k = ks * 32 + (lane >> 4) * 8 + j;
      const int n = ti * 16 + (lane & 15);
      float v;
      if (n < 128) v = W[k * 128 + n];
      else if (n < 132) v = fS[k * 4 + (n - 128)];
      else if (n < 136) v = fD[k * 4 + (n - 132)];
      else v = 0.f;
      out[i] = f2bf(v);
    }
    return;
  }

  if (b < 4 + PT_BLK) {
    // ---------------- pre_t path (64 rows/block, 4r x 8c / thread) ----------------
    float (*s_xt)[68] = (float(*)[68])smem;                 // 64 x 68 x4 = 17408
    float (*s_W)[128] = (float(*)[128])(smem + 17408);      // 32 x 128 x4 = 16384
    float* s_fold     = (float*)(smem + 17408 + 16384);     // 512 x4 = 2048
    const int row0 = (b - 4) * 64;
    // stage x_t transposed: s_xt[k][row]
    for (int g = 0; g < 4; ++g) {
      const int lr = g * 16 + (t >> 4);
      const int k4 = (t & 15) * 4;
      const int grow = row0 + lr;
      float4 f = make_float4(0.f, 0.f, 0.f, 0.f);
      if (grow < NT) f = *(const float4*)(x_t + (size_t)grow * 64 + k4);
      s_xt[k4 + 0][lr] = f.x; s_xt[k4 + 1][lr] = f.y;
      s_xt[k4 + 2][lr] = f.z; s_xt[k4 + 3][lr] = f.w;
    }
    // fold_cd self-compute (removes prep dependency)
    if (t < 128) {
      for (int hh = 0; hh < 4; ++hh) {
        float s = 0.f;
        for (int c = 0; c < 32; ++c)
          s = fmaf(Wcd[t * 128 + hh * 32 + c], attD[hh * 32 + c], s);
        s_fold[t * 4 + hh] = s * LOG2E;
      }
    }
    const int rg = t >> 4;        // row group: rows rg*4 .. rg*4+4
    const int cg = t & 15;        // col groups: cg*4 and cg*4+64
    float acc[4][8];
    for (int r = 0; r < 4; ++r)
      for (int j = 0; j < 8; ++j)
        acc[r][j] = bpt[cg * 4 + (j & 3) + (j >> 2) * 64];
    for (int kc = 0; kc < 64; kc += 32) {
      for (int j = 0; j < 4; ++j) {
        const int idx = t + j * 256;
        const int k = idx >> 5, c4 = (idx & 31) * 4;
        *(float4*)&s_W[k][c4] = *(const float4*)(Wpt + (size_t)(kc + k) * 128 + c4);
      }
      __syncthreads();
#pragma unroll 8
      for (int k = 0; k < 32; ++k) {
        const float4 xa = *(const float4*)&s_xt[kc + k][rg * 4];
        const float4 w0 = *(const float4*)&s_W[k][cg * 4];
        const float4 w1 = *(const float4*)&s_W[k][cg * 4 + 64];
        const float xr[4] = {xa.x, xa.y, xa.z, xa.w};
        for (int r = 0; r < 4; ++r) {
          acc[r][0] = fmaf(xr[r], w0.x, acc[r][0]);
          acc[r][1] = fmaf(xr[r], w0.y, acc[r][1]);
          acc[r][2] = fmaf(xr[r], w0.z, acc[r][2]);
          acc[r][3] = fmaf(xr[r], w0.w, acc[r][3]);
          acc[r][4] = fmaf(xr[r], w1.x, acc[r][4]);
          acc[r][5] = fmaf(xr[r], w1.y, acc[r][5]);
          acc[r][6] = fmaf(xr[r], w1.z, acc[r][6]);
          acc[r][7] = fmaf(xr[r], w1.w, acc[r][7]);
        }
      }
      __syncthreads();
    }
    // epilogue: relu + h_t(bf16) + aD fold + 16-lane reduce
    float4 fc0[2], fc1[2];
    fc0[0] = *(const float4*)&s_fold[(cg * 4 + 0) * 4];
    // (per-col fold vectors read inside the loop; broadcast-cheap)
    (void)fc0; (void)fc1;
    for (int r = 0; r < 4; ++r) {
      const int grow = row0 + rg * 4 + r;
      float v[8];
      for (int j = 0; j < 8; ++j) v[j] = fmaxf(acc[r][j], 0.f);
      float p0 = 0.f, p1 = 0.f, p2 = 0.f, p3 = 0.f;
      for (int j = 0; j < 8; ++j) {
        const int col = cg * 4 + (j & 3) + ((j >> 2) * 64);
        const float4 f4 = *(const float4*)&s_fold[col * 4];
        p0 = fmaf(v[j], f4.x, p0); p1 = fmaf(v[j], f4.y, p1);
        p2 = fmaf(v[j], f4.z, p2); p3 = fmaf(v[j], f4.w, p3);
      }
      if (grow < NT) {
        uint2 pk;
        pk.x = (u32)f2bf(v[0]) | ((u32)f2bf(v[1]) << 16);
        pk.y = (u32)f2bf(v[2]) | ((u32)f2bf(v[3]) << 16);
        *(uint2*)(h_t + (size_t)grow * 128 + cg * 4) = pk;
        pk.x = (u32)f2bf(v[4]) | ((u32)f2bf(v[5]) << 16);
        pk.y = (u32)f2bf(v[6]) | ((u32)f2bf(v[7]) << 16);
        *(uint2*)(h_t + (size_t)grow * 128 + cg * 4 + 64) = pk;
      }
      for (int m = 1; m < 16; m <<= 1) {
        p0 += __shfl_xor(p0, m); p1 += __shfl_xor(p1, m);
        p2 += __shfl_xor(p2, m); p3 += __shfl_xor(p3, m);
      }
      if (cg == 0 && grow < NT)
        *(float4*)(aD + (size_t)grow * 4) = make_float4(p0, p1, p2, p3);
    }
    return;
  }

  // ---------------- ctx path (64 rows/block, 4r x 8c / thread) ----------------
  {
    float (*s_ht)[68]  = (float(*)[68])smem;                // 128 x 68 x4 = 34816
    float (*s_W2)[128] = (float(*)[128])(smem + 34816);     // 16384 (total 51200)
    float (*s_xc)[68]  = (float(*)[68])smem;                // alias: dead before s_ht writes
    const int row0 = (b - 4 - PT_BLK) * 64;
    // stage x_c transposed: s_xc[k][row], k 0..32
    for (int g = 0; g < 2; ++g) {
      const int lr = g * 32 + (t >> 3);
      const int k4 = (t & 7) * 4;
      const int grow = row0 + lr;
      float4 f = make_float4(0.f, 0.f, 0.f, 0.f);
      if (grow < NC) f = *(const float4*)(x_c + (size_t)grow * 32 + k4);
      s_xc[k4 + 0][lr] = f.x; s_xc[k4 + 1][lr] = f.y;
      s_xc[k4 + 2][lr] = f.z; s_xc[k4 + 3][lr] = f.w;
    }
    // load Wpc [32][128]
    for (int j = 0; j < 4; ++j) {
      const int idx = t + j * 256;
      const int k = idx >> 5, c4 = (idx & 31) * 4;
      *(float4*)&s_W2[k][c4] = *(const float4*)(Wpc + (size_t)k * 128 + c4);
    }
    __syncthreads();
    const int rg = t >> 4, cg = t & 15;
    float acc1[4][8];
    for (int r = 0; r < 4; ++r)
      for (int j = 0; j < 8; ++j)
        acc1[r][j] = bpc[cg * 4 + (j & 3) + (j >> 2) * 64];
#pragma unroll 8
    for (int k = 0; k < 32; ++k) {
      const float4 xa = *(const float4*)&s_xc[k][rg * 4];
      const float4 w0 = *(const float4*)&s_W2[k][cg * 4];
      const float4 w1 = *(const float4*)&s_W2[k][cg * 4 + 64];
      const float xr[4] = {xa.x, xa.y, xa.z, xa.w};
      for (int r = 0; r < 4; ++r) {
        acc1[r][0] = fmaf(xr[r], w0.x, acc1[r][0]);
        acc1[r][1] = fmaf(xr[r], w0.y, acc1[r][1]);
        acc1[r][2] = fmaf(xr[r], w0.z, acc1[r][2]);
        acc1[r][3] = fmaf(xr[r], w0.w, acc1[r][3]);
        acc1[r][4] = fmaf(xr[r], w1.x, acc1[r][4]);
        acc1[r][5] = fmaf(xr[r], w1.y, acc1[r][5]);
        acc1[r][6] = fmaf(xr[r], w1.z, acc1[r][6]);
        acc1[r][7] = fmaf(xr[r], w1.w, acc1[r][7]);
      }
    }
    __syncthreads();                 // s_xc dead; safe to overwrite with s_ht
    // write relu(h) TRANSPOSED: s_ht[col][row]
    for (int r = 0; r < 4; ++r) {
      const int lr = rg * 4 + r;
      for (int j = 0; j < 8; ++j) {
        const int col = cg * 4 + (j & 3) + ((j >> 2) * 64);
        s_ht[col][lr] = fmaxf(acc1[r][j], 0.f);
      }
    }
    // load Wcs chunk 0
    for (int j = 0; j < 4; ++j) {
      const int idx = t + j * 256;
      const int k = idx >> 5, c4 = (idx & 31) * 4;
      *(float4*)&s_W2[k][c4] = *(const float4*)(Wcs + (size_t)k * 128 + c4);
    }
    __syncthreads();
    float acc2[4][8];
    for (int r = 0; r < 4; ++r)
      for (int j = 0; j < 8; ++j) acc2[r][j] = 0.f;
    for (int kc = 0; kc < 128; kc += 32) {
#pragma unroll 8
      for (int k = 0; k < 32; ++k) {
        const float4 xa = *(const float4*)&s_ht[kc + k][rg * 4];
        const float4 w0 = *(const float4*)&s_W2[k][cg * 4];
        const float4 w1 = *(const float4*)&s_W2[k][cg * 4 + 64];
        const float xr[4] = {xa.x, xa.y, xa.z, xa.w};
        for (int r = 0; r < 4; ++r) {
          acc2[r][0] = fmaf(xr[r], w0.x, acc2[r][0]);
          acc2[r][1] = fmaf(xr[r], w0.y, acc2[r][1]);
          acc2[r][2] = fmaf(xr[r], w0.z, acc2[r][2]);
          acc2[r][3] = fmaf(xr[r], w0.w, acc2[r][3]);
          acc2[r][4] = fmaf(xr[r], w1.x, acc2[r][4]);
          acc2[r][5] = fmaf(xr[r], w1.y, acc2[r][5]);
          acc2[r][6] = fmaf(xr[r], w1.z, acc2[r][6]);
          acc2[r][7] = fmaf(xr[r], w1.w, acc2[r][7]);
        }
      }
      if (kc < 96) {
        __syncthreads();
        for (int j = 0; j < 4; ++j) {
          const int idx = t + j * 256;
          const int k = idx >> 5, c4 = (idx & 31) * 4;
          *(float4*)&s_W2[k][c4] = *(const float4*)(Wcs + (size_t)(kc + 32 + k) * 128 + c4);
        }
        __syncthreads();
      }
    }
    // epilogue: hc_bf(bf16) + a_s_ct logits (per-head 8-lane reduce)
    const int h2 = cg >> 3;
    const float4 at0 = *(const float4*)(attS + cg * 4);
    const float4 at1 = *(const float4*)(attS + cg * 4 + 64);
    for (int r = 0; r < 4; ++r) {
      const int grow = row0 + rg * 4 + r;
      float pa = acc2[r][0] * at0.x + acc2[r][1] * at0.y +
                 acc2[r][2] * at0.z + acc2[r][3] * at0.w;
      float pb = acc2[r][4] * at1.x + acc2[r][5] * at1.y +
                 acc2[r][6] * at1.z + acc2[r][7] * at1.w;
      if (grow < NC) {
        uint2 pk;
        pk.x = (u32)f2bf(acc2[r][0]) | ((u32)f2bf(acc2[r][1]) << 16);
        pk.y = (u32)f2bf(acc2[r][2]) | ((u32)f2bf(acc2[r][3]) << 16);
        *(uint2*)(hc_bf + (size_t)grow * 128 + cg * 4) = pk;
        pk.x = (u32)f2bf(acc2[r][4]) | ((u32)f2bf(acc2[r][5]) << 16);
        pk.y = (u32)f2bf(acc2[r][6]) | ((u32)f2bf(acc2[r][7]) << 16);
        *(uint2*)(hc_bf + (size_t)grow * 128 + cg * 4 + 64) = pk;
      }
      for (int m = 1; m < 8; m <<= 1) {
        pa += __shfl_xor(pa, m);
        pb += __shfl_xor(pb, m);
      }
      if ((cg & 7) == 0 && grow < NC) {
        aS_c[(size_t)grow * 4 + h2] = pa * LOG2E;
        aS_c[(size_t)grow * 4 + 2 + h2] = pb * LOG2E;
      }
    }
  }
}

// ---------- scan2_blk: 4096-chunk exclusive scan (partial) + chunk totals ----------
__global__ __launch_bounds__(256) void scan2_blk_kernel(const int* __restrict__ in,
    int* __restrict__ out, int* __restrict__ bsum)
{
  const int t = threadIdx.x, b = blockIdx.x;
  const int idx = b * 4096 + t * 16;
  int v[16];
  int s = 0;
  if (idx < TOTC) {                     // TOTC % 16 == 0, so full 16 are safe
#pragma unroll
    for (int q = 0; q < 4; ++q) {
      const int4 qq = *(const int4*)(in + idx + q * 4);
      v[q * 4 + 0] = s; s += qq.x;
      v[q * 4 + 1] = s; s += qq.y;
      v[q * 4 + 2] = s; s += qq.z;
      v[q * 4 + 3] = s; s += qq.w;
    }
  } else {
    for (int j = 0; j < 16; ++j) v[j] = 0;
  }
  __shared__ int sh[256];
  sh[t] = s;
  __syncthreads();
  for (int d = 1; d < 256; d <<= 1) {
    const int u = (t >= d) ? sh[t - d] : 0;
    __syncthreads();
    sh[t] += u;
    __syncthreads();
  }
  const int excl = (t == 0) ? 0 : sh[t - 1];
  if (idx < TOTC) {
#pragma unroll
    for (int q = 0; q < 4; ++q) {
      int4 qo;
      qo.x = excl + v[q * 4 + 0]; qo.y = excl + v[q * 4 + 1];
      qo.z = excl + v[q * 4 + 2]; qo.w = excl + v[q * 4 + 3];
      *(int4*)(out + idx + q * 4) = qo;
    }
  }
  if (t == 255) bsum[b] = sh[255];
}

// ---------- K_C: bin (256 blocks) ∪ mfma_logits2 (1563 blocks) ----------
__global__ __launch_bounds__(256) void bin_logits2_kernel(
    const int* __restrict__ tt_src, const int* __restrict__ tt_dst,
    const int* __restrict__ ect_s, const int* __restrict__ ect_d,
    const int* __restrict__ scanned, const int* __restrict__ bsum, u32* __restrict__ bin,
    const short* __restrict__ A, const short* __restrict__ Bsd, const short* __restrict__ Bds,
    u16* __restrict__ hs, float* __restrict__ aSsd, float* __restrict__ aDsd,
    u16* __restrict__ hd, float* __restrict__ aSds, float* __restrict__ aDds, int M)
{
  __shared__ __align__(16) float ldsf[4][16][148];
  const int t = threadIdx.x;

  if (blockIdx.x < NBLK) {
    // ---------------- bin path ----------------
    int* cur = (int*)&ldsf[0][0][0];        // 2346 ints
    int* s_bpre = cur + 3 * NBK;            // 256 ints
    compute_bpre(bsum, s_bpre);
    const int b = blockIdx.x;
    for (int i = t; i < 3 * NBK; i += 256) {
      const int idx = i * NBLK + b;
      cur[i] = scanned[idx] + s_bpre[idx >> 12];
    }
    __syncthreads();
    const int lo = b * CHT, hi = min(lo + CHT, ETT);
    for (int i = lo + t; i < hi; i += 256) {
      const int s = tt_src[i], d = tt_dst[i];
      int p = atomicAdd(&cur[d >> 7], 1);
      bin[p] = ((u32)(d & 127) << 17) | (u32)s;
      p = atomicAdd(&cur[NBK + (s >> 7)], 1);
      bin[p] = ((u32)(s & 127) << 17) | (u32)d;
    }
    const int lo2 = b * CHC, hi2 = min(lo2 + CHC, ECT);
    for (int i = lo2 + t; i < hi2; i += 256) {
      const int s = ect_s[i], d = ect_d[i];
      const int p = atomicAdd(&cur[2 * NBK + (d >> 7)], 1);
      bin[p] = ((u32)(d & 127) << 17) | (u32)s;
    }
    return;
  }

  // ---------------- logits2 path ----------------
  float (*lds)[16][148] = ldsf;
  const int blk = blockIdx.x - NBLK;
  const int wv = t >> 6, lane = t & 63;
  const int quad = lane >> 4, l16 = lane & 15;
  const int row0 = blk * 64 + wv * 16;
  const int arow = min(row0 + l16, M - 1);
  const short* ap = A + (size_t)arow * 128 + quad * 8;
  bf16x8 af[4];
  for (int ks = 0; ks < 4; ++ks) af[ks] = *(const bf16x8*)(ap + ks * 32);
  const int row = row0 + l16;
  const int idx = lane & 7, rr = lane >> 3;
  for (int pass = 0; pass < 2; ++pass) {
    const short* B = pass ? Bds : Bsd;
    u16* outb = pass ? hd : hs;
    float* aS = pass ? aSds : aSsd;
    float* aD = pass ? aDds : aDsd;
    f32x4 acc[9];
    for (int ti = 0; ti < 9; ++ti) acc[ti] = (f32x4){0.f, 0.f, 0.f, 0.f};
    for (int ks = 0; ks < 4; ++ks)
      for (int ti = 0; ti < 9; ++ti) {
        const bf16x8 bf = *(const bf16x8*)(B + ((ti * 4 + ks) * 64 + lane) * 8);
        acc[ti] = __builtin_amdgcn_mfma_f32_16x16x32_bf16(af[ks], bf, acc[ti], 0, 0, 0);
      }
    for (int ti = 0; ti < 9; ++ti)
      for (int r = 0; r < 4; ++r)
        lds[wv][quad * 4 + r][ti * 16 + l16] = acc[ti][r];
    __syncthreads();
    if (row < M) {
      for (int g = 0; g < 8; ++g) {
        const f32x4 v = *(const f32x4*)&lds[wv][l16][g * 16 + quad * 4];
        uint2 pk;
        pk.x = (u32)f2bf(v[0]) | ((u32)f2bf(v[1]) << 16);
        pk.y = (u32)f2bf(v[2]) | ((u32)f2bf(v[3]) << 16);
        *(uint2*)(outb + (size_t)row * 128 + g * 16 + quad * 4) = pk;
      }
    }
    for (int p = 0; p < 2; ++p) {
      const int lr = p * 8 + rr;
      const int n = row0 + lr;
      if (n < M) {
        const float v = lds[wv][lr][128 + idx];
        if (idx < 4) aS[(size_t)n * 4 + idx] = v;
        else aD[(size_t)n * 4 + idx - 4] = v;
      }
    }
    __syncthreads();
  }
}

// ---------- bucket_fill: self-computed bpre + LDS-staged coalesced el output ----------
__global__ __launch_bounds__(256) void bucket_fill_kernel(const int* __restrict__ scanned,
    const int* __restrict__ bsum, const u32* __restrict__ bin,
    int* __restrict__ offs, int* __restrict__ big_el)
{
  __shared__ int s_cnt[128], s_exc[128], s_cur[128], s_bpre[256];
  __shared__ int s_el[FILL_CAP];
  const int t = threadIdx.x;
  compute_bpre(bsum, s_bpre);
  const int rel = blockIdx.x / NBK;
  const int bucket = blockIdx.x - rel * NBK;
  if (t < 128) s_cnt[t] = 0;
  const int bi = blockIdx.x * NBLK;
  const int base = scanned[bi] + s_bpre[bi >> 12];
  const int nxt = (blockIdx.x == 3 * NBK - 1)
                      ? (2 * ETT + ECT)
                      : scanned[bi + NBLK] + s_bpre[(bi + NBLK) >> 12];
  __syncthreads();
  const int size = nxt - base;
  for (int i = t; i < size; i += 256)
    atomicAdd(&s_cnt[bin[base + i] >> 17], 1);
  __syncthreads();
  if (t < 128) s_exc[t] = s_cnt[t];
  __syncthreads();
  for (int d = 1; d < 128; d <<= 1) {
    int v = 0;
    if (t < 128 && t >= d) v = s_exc[t - d];
    __syncthreads();
    if (t < 128) s_exc[t] += v;
    __syncthreads();
  }
  const int relbase = rel * ETT;
  const int obase = base - relbase;
  int* off_rel = offs + (size_t)rel * OFFS;
  const int node0 = bucket * 128;
  if (t < 128) {
    const int excl = s_exc[t] - s_cnt[t];
    s_cur[t] = excl;                    // bucket-LOCAL cursor
    if (node0 + t < NT) off_rel[node0 + t] = obase + excl;
  }
  if (t == 0 && bucket == NBK - 1) off_rel[NT] = obase + size;
  __syncthreads();
  int* el_rel = big_el + relbase;
  if (size <= FILL_CAP) {
    for (int i = t; i < size; i += 256) {
      const u32 e = bin[base + i];
      const int pos = atomicAdd(&s_cur[e >> 17], 1);
      s_el[pos] = (int)(e & 0x1FFFFu);
    }
    __syncthreads();
    for (int i = t; i < size; i += 256)
      el_rel[obase + i] = s_el[i];
  } else {
    for (int i = t; i < size; i += 256) {
      const u32 e = bin[base + i];
      const int pos = atomicAdd(&s_cur[e >> 17], 1);
      el_rel[obase + pos] = (int)(e & 0x1FFFFu);
    }
  }
}

// ---------- MFMA GEMM, N=128 (8 tiles) + bias -> fp32 out ----------
__global__ __launch_bounds__(256) void mfma_out_kernel(
    const short* __restrict__ A, const short* __restrict__ B,
    const float* __restrict__ bias, float* __restrict__ out, int M)
{
  __shared__ __align__(16) float lds[4][16][132];
  const int wv = threadIdx.x >> 6, lane = threadIdx.x & 63;
  const int quad = lane >> 4, l16 = lane & 15;
  const int row0 = blockIdx.x * 64 + wv * 16;
  const int arow = min(row0 + l16, M - 1);
  const short* ap = A + (size_t)arow * 128 + quad * 8;
  bf16x8 af[4];
  for (int ks = 0; ks < 4; ++ks) af[ks] = *(const bf16x8*)(ap + ks * 32);
  f32x4 acc[8];
  for (int t = 0; t < 8; ++t) acc[t] = (f32x4){0.f, 0.f, 0.f, 0.f};
  for (int ks = 0; ks < 4; ++ks)
    for (int t = 0; t < 8; ++t) {
      const bf16x8 bf = *(const bf16x8*)(B + ((t * 4 + ks) * 64 + lane) * 8);
      acc[t] = __builtin_amdgcn_mfma_f32_16x16x32_bf16(af[ks], bf, acc[t], 0, 0, 0);
    }
  for (int t = 0; t < 8; ++t)
    for (int r = 0; r < 4; ++r)
      lds[wv][quad * 4 + r][t * 16 + l16] = acc[t][r];
  __syncthreads();
  const int row = row0 + l16;
  if (row < M) {
    for (int g = 0; g < 8; ++g) {
      const int col = g * 16 + quad * 4;
      f32x4 v = *(const f32x4*)&lds[wv][l16][col];
      const f32x4 b4 = *(const f32x4*)(bias + col);
      v = v + b4;
      *(f32x4*)(out + (size_t)row * 128 + col) = v;
    }
  }
}

// ---------- K5: fused 3-relation gather; 16-lane group per dst, 8 ch/lane ----------
// Round-0 depth-1 pipeline (fastest measured) with exp2f (logits LOG2E-prescaled).
// Gather is at its structural memory roofline (~3.5 TB/s on scattered 256B rows);
// deeper pipelining, occupancy, and request reduction all measured null (R0/R2/R3).
__device__ __forceinline__ void gat_pipe16(const int* __restrict__ off,
    const int* __restrict__ el, const float* __restrict__ aS, const float* __restrict__ aD,
    const u16* __restrict__ hb, int d, int h, int cb, int self_loop, float w,
    float* __restrict__ acc)
{
  const float ad = aD[(size_t)d * 4 + h];
  const int beg = off[d];
  const int m = off[d + 1] - beg;     // real edges
  const int cnt = m + self_loop;
  if (cnt <= 0) return;
  float den = 0.f;
  float a0 = 0.f, a1 = 0.f, a2 = 0.f, a3 = 0.f, a4 = 0.f, a5 = 0.f, a6 = 0.f, a7 = 0.f;
  int sB = (1 < m) ? el[beg + 1] : d;
  {
    const int sA0 = (0 < m) ? el[beg] : d;
    float eA = aS[(size_t)sA0 * 4 + h];
    uint4 pA = *(const uint4*)(hb + (size_t)sA0 * 128 + cb);
    for (int k = 0; k < cnt; ++k) {
      const int sC = (k + 2 < m) ? el[beg + k + 2] : d;
      const float eB = aS[(size_t)sB * 4 + h];
      const uint4 pB = *(const uint4*)(hb + (size_t)sB * 128 + cb);
      float ea = eA + ad;
      ea = ea > 0.f ? ea : SLOPE * ea;
      const float ex = exp2f(ea);
      den += ex;
      a0 = fmaf(ex, lof(pA.x), a0); a1 = fmaf(ex, hif(pA.x), a1);
      a2 = fmaf(ex, lof(pA.y), a2); a3 = fmaf(ex, hif(pA.y), a3);
      a4 = fmaf(ex, lof(pA.z), a4); a5 = fmaf(ex, hif(pA.z), a5);
      a6 = fmaf(ex, lof(pA.w), a6); a7 = fmaf(ex, hif(pA.w), a7);
      eA = eB; pA = pB; sB = sC;
    }
  }
  const float s = w / den;            // den > 0 since cnt > 0
  acc[0] = fmaf(a0, s, acc[0]); acc[1] = fmaf(a1, s, acc[1]);
  acc[2] = fmaf(a2, s, acc[2]); acc[3] = fmaf(a3, s, acc[3]);
  acc[4] = fmaf(a4, s, acc[4]); acc[5] = fmaf(a5, s, acc[5]);
  acc[6] = fmaf(a6, s, acc[6]); acc[7] = fmaf(a7, s, acc[7]);
}

__global__ __launch_bounds__(256) void gather_all_kernel(
    const int* __restrict__ off_f, const int* __restrict__ el_f,
    const float* __restrict__ aS_sd, const float* __restrict__ aD_sd, const u16* __restrict__ hs,
    const int* __restrict__ off_r, const int* __restrict__ el_r,
    const float* __restrict__ aS_ds, const float* __restrict__ aD_ds, const u16* __restrict__ hd,
    const int* __restrict__ off_c, const int* __restrict__ el_c,
    const float* __restrict__ aS_ct, const float* __restrict__ aD_ct, const u16* __restrict__ hc,
    const u16* __restrict__ skip, const float* __restrict__ cbias, u16* __restrict__ x)
{
  const int d = blockIdx.x * 16 + (threadIdx.x >> 4);
  if (d >= NT) return;
  const int lg = threadIdx.x & 15;    // lane in group
  const int h = lg >> 2;              // head for this lane's channels
  const int cb = lg * 8;              // channel base (8 channels per lane)
  float acc[8];
  for (int i = 0; i < 8; ++i) acc[i] = 0.f;
  gat_pipe16(off_f, el_f, aS_sd, aD_sd, hs, d, h, cb, 1, 0.25f, acc);
  gat_pipe16(off_r, el_r, aS_ds, aD_ds, hd, d, h, cb, 1, 0.25f, acc);
  gat_pipe16(off_c, el_c, aS_ct, aD_ct, hc, d, h, cb, 0, 0.5f, acc);
  const uint4 sk = *(const uint4*)(skip + (size_t)d * 128 + cb);
  const float4 cb0 = *(const float4*)(cbias + cb);
  const float4 cb1 = *(const float4*)(cbias + cb + 4);
  const float o0 = fmaxf(acc[0] + cb0.x + lof(sk.x), 0.f);
  const float o1 = fmaxf(acc[1] + cb0.y + hif(sk.x), 0.f);
  const float o2 = fmaxf(acc[2] + cb0.z + lof(sk.y), 0.f);
  const float o3 = fmaxf(acc[3] + cb0.w + hif(sk.y), 0.f);
  const float o4 = fmaxf(acc[4] + cb1.x + lof(sk.z), 0.f);
  const float o5 = fmaxf(acc[5] + cb1.y + hif(sk.z), 0.f);
  const float o6 = fmaxf(acc[6] + cb1.z + lof(sk.w), 0.f);
  const float o7 = fmaxf(acc[7] + cb1.w + hif(sk.w), 0.f);
  uint4 r;
  r.x = (u32)f2bf(o0) | ((u32)f2bf(o1) << 16);
  r.y = (u32)f2bf(o2) | ((u32)f2bf(o3) << 16);
  r.z = (u32)f2bf(o4) | ((u32)f2bf(o5) << 16);
  r.w = (u32)f2bf(o6) | ((u32)f2bf(o7) << 16);
  *(uint4*)(x + (size_t)d * 128 + cb) = r;
}

extern "C" void kernel_launch(void* const* d_in, const int* in_sizes, int n_in,
                              void* d_out, int out_size, void* d_ws, size_t ws_size,
                              hipStream_t stream)
{
  const float* x_t   = (const float*)d_in[0];
  const float* x_c   = (const float*)d_in[1];
  const int*   e_tt  = (const int*)d_in[2];
  const int*   ect_s = (const int*)d_in[3];
  const int*   ect_d = (const int*)d_in[4];
  const float* Wpt = (const float*)d_in[5];   const float* bpt = (const float*)d_in[6];
  const float* Wpc = (const float*)d_in[7];   const float* bpc = (const float*)d_in[8];
  const float* Wsd = (const float*)d_in[9];   const float* As_sd = (const float*)d_in[10];
  const float* Ad_sd = (const float*)d_in[11]; const float* bsd = (const float*)d_in[12];
  const float* Wds = (const float*)d_in[13];  const float* As_ds = (const float*)d_in[14];
  const float* Ad_ds = (const float*)d_in[15]; const float* bds = (const float*)d_in[16];
  const float* Wcs = (const float*)d_in[17];  const float* Wcd = (const float*)d_in[18];
  const float* As_ct = (const float*)d_in[19]; const float* Ad_ct = (const float*)d_in[20];
  const float* bct = (const float*)d_in[21];
  const float* Wout = (const float*)d_in[22]; const float* bout = (const float*)d_in[23];

  // workspace (~140 MB)
  char* p = (char*)d_ws;
  size_t off = 0;
  auto alloc = [&](size_t bytes) { char* r = p + off; off += (bytes + 255) & ~(size_t)255; return r; };
  u16* ht_bf   = (u16*)alloc((size_t)NT * 128 * 2);
  u16* hs_bf   = (u16*)alloc((size_t)NT * 128 * 2);
  u16* hd_bf   = (u16*)alloc((size_t)NT * 128 * 2);
  u16* hc_bf   = (u16*)alloc((size_t)NC * 128 * 2);
  u16* x_bf    = (u16*)alloc((size_t)NT * 128 * 2);
  float* aS_sd = (float*)alloc((size_t)NT * 4 * 4);
  float* aD_sd = (float*)alloc((size_t)NT * 4 * 4);
  float* aS_ds = (float*)alloc((size_t)NT * 4 * 4);
  float* aD_ds = (float*)alloc((size_t)NT * 4 * 4);
  float* aS_ct = (float*)alloc((size_t)NC * 4 * 4);
  float* aD_ct = (float*)alloc((size_t)NT * 4 * 4);
  int* cntblk  = (int*)alloc((size_t)TOTC * 4);
  int* scanned = (int*)alloc((size_t)TOTC * 4);
  u32* bin     = (u32*)alloc((size_t)(2 * ETT + ECT) * 4);
  int* big_el  = (int*)alloc((size_t)(2 * ETT + ECT) * 4);
  int* offs    = (int*)alloc((size_t)3 * OFFS * 4);
  int* bsum    = (int*)alloc((size_t)NSB * 4);
  float* cbias   = (float*)alloc(128 * 4);
  u16* bfrag_sd  = (u16*)alloc((size_t)9 * 4 * 64 * 8 * 2);
  u16* bfrag_ds  = (u16*)alloc((size_t)9 * 4 * 64 * 8 * 2);
  u16* bfrag_out = (u16*)alloc((size_t)8 * 4 * 64 * 8 * 2);

  int* off_f = offs;
  int* off_r = offs + OFFS;
  int* off_c = offs + 2 * OFFS;
  int* el_f = big_el;
  int* el_r = big_el + ETT;
  int* el_c = big_el + 2 * ETT;

  const int* tt_src = e_tt;
  const int* tt_dst = e_tt + ETT;

  const int gM = (NT + 63) / 64;       // 1563 (MFMA blocks)

  // K_A: hist ∪ prep ∪ pre_t ∪ ctx (independent paths, one dispatch)
  transform_hist_kernel<<<NBLK + 4 + PT_BLK + CT_BLK, 256, 0, stream>>>(
      tt_src, tt_dst, ect_d, cntblk,
      Wsd, As_sd, Ad_sd, Wds, As_ds, Ad_ds, Wout,
      bfrag_sd, bfrag_ds, bfrag_out,
      Wcd, Ad_ct, bsd, bds, bct, cbias,
      x_t, Wpt, bpt, ht_bf, aD_ct,
      x_c, Wpc, bpc, Wcs, As_ct, hc_bf, aS_ct);

  // scan (147 blocks; top-level prefix recomputed by consumers in LDS)
  scan2_blk_kernel<<<NSB, 256, 0, stream>>>(cntblk, scanned, bsum);

  // K_C: bin ∪ sd/ds MFMA GEMMs+logits (independent, one dispatch)
  bin_logits2_kernel<<<NBLK + gM, 256, 0, stream>>>(
      tt_src, tt_dst, ect_s, ect_d, scanned, bsum, bin,
      (const short*)ht_bf, (const short*)bfrag_sd, (const short*)bfrag_ds,
      hs_bf, aS_sd, aD_sd, hd_bf, aS_ds, aD_ds, NT);

  // bucket_fill: CSR finalize (LDS-staged coalesced writes)
  bucket_fill_kernel<<<3 * NBK, 256, 0, stream>>>(scanned, bsum, bin, offs, big_el);

  // fused gather (sd + ds + ct + cbias + skip + relu) -> x_bf
  gather_all_kernel<<<(NT + 15) / 16, 256, 0, stream>>>(
      off_f, el_f, aS_sd, aD_sd, hs_bf,
      off_r, el_r, aS_ds, aD_ds, hd_bf,
      off_c, el_c, aS_ct, aD_ct, hc_bf,
      ht_bf, cbias, x_bf);

  // final MFMA GEMM -> d_out (fp32)
  mfma_out_kernel<<<gM, 256, 0, stream>>>((const short*)x_bf, (const short*)bfrag_out,
                                          bout, (float*)d_out, NT);
}